// Round 9
// baseline (493.937 us; speedup 1.0000x reference)
//
#include <hip/hip_runtime.h>
#include <hip/hip_bf16.h>
#include <math.h>

#define BATCH 2
#define SEQL 2048
#define T 4096            // BATCH*SEQL tokens
#define DMODEL 1024
#define DINNER 2048
#define DSTATE 128
#define NH 32
#define HD 64
#define DPROJ2 4352       // z (2048) + xBC (2304); dt handled separately in fp32
#define CONVCH 2304
#define NCH 16            // chunks per sequence
#define CHUNK 128
#define EPS 1e-5f

#define N_INW ((size_t)DPROJ2 * DMODEL)   // 4,456,448
#define N_OUTW ((size_t)DMODEL * DINNER)  // 2,097,152
#define N_ST ((size_t)BATCH * NCH * NH * HD * DSTATE)  // 8,388,608 per dir
#define F2B_BLOCKS 10752   // (2*N_INW + N_OUTW)/4/256
#define TW_BLOCKS 1024     // 32 x 16 x 2

typedef unsigned short u16;
typedef __bf16 bf16x8 __attribute__((ext_vector_type(8)));
typedef float f32x4 __attribute__((ext_vector_type(4)));

__device__ __forceinline__ u16 f2b(float f) {
    union { float f; unsigned u; } v; v.f = f;
    unsigned r = v.u + 0x7fffu + ((v.u >> 16) & 1u);
    return (u16)(r >> 16);
}
__device__ __forceinline__ float b2f(u16 b) {
    union { unsigned u; float f; } v; v.u = ((unsigned)b) << 16;
    return v.f;
}
__device__ __forceinline__ float lo16f(unsigned u) {
    union { unsigned x; float f; } v; v.x = u << 16; return v.f;
}
__device__ __forceinline__ float hi16f(unsigned u) {
    union { unsigned x; float f; } v; v.x = u & 0xffff0000u; return v.f;
}
__device__ __forceinline__ int flipseq(int r) {
    return (r & ~(SEQL - 1)) | ((SEQL - 1) - (r & (SEQL - 1)));
}
__device__ __forceinline__ void gload16(const u16* g, u16* l) {
    __builtin_amdgcn_global_load_lds(
        (const __attribute__((address_space(1))) void*)g,
        (__attribute__((address_space(3))) void*)l, 16, 0, 0);
}

#define FENCE asm volatile("" ::: "memory")

// ---------------- merged prep: [0,1024) rmsnorm+dt rows; [1024,..) weight f2b/transpose ----------------
__global__ __launch_bounds__(256) void k_prep(
    const float* __restrict__ x, const float* __restrict__ w,
    const float* __restrict__ f_in_w, const float* __restrict__ b_in_w,
    const float* __restrict__ dtb_f, const float* __restrict__ dtb_b,
    u16* __restrict__ outb, float* __restrict__ dt,
    const float* __restrict__ out_w_blk,
    const float* __restrict__ f_out_w, const float* __restrict__ b_out_w,
    u16* __restrict__ d_inwb, u16* __restrict__ d_owbb, u16* __restrict__ d_fowT)
{
    __shared__ float xs[4][1024];
    __shared__ u16 t[64][65];
    int bid0 = blockIdx.x;
    int tid = threadIdx.x;
    if (bid0 < 1024) {
        // ---- rmsnorm + dt path ----
        int r0 = bid0 * 4;
        int lane = tid & 63, wv = tid >> 6;
        int row = r0 + wv;
        const float* xr = x + (size_t)row * DMODEL;
        float4 v[4];
        float ss = 0.f;
        #pragma unroll
        for (int i = 0; i < 4; ++i) {
            v[i] = *(const float4*)(xr + (i * 64 + lane) * 4);
            ss += v[i].x * v[i].x + v[i].y * v[i].y + v[i].z * v[i].z + v[i].w * v[i].w;
        }
        #pragma unroll
        for (int off = 32; off > 0; off >>= 1) ss += __shfl_down(ss, off);
        ss = __shfl(ss, 0);
        float sc = rsqrtf(ss / DMODEL + EPS);
        #pragma unroll
        for (int i = 0; i < 4; ++i) {
            int c = (i * 64 + lane) * 4;
            float4 wv4 = *(const float4*)(w + c);
            ushort4 o;
            o.x = f2b(v[i].x * sc * wv4.x);
            o.y = f2b(v[i].y * sc * wv4.y);
            o.z = f2b(v[i].z * sc * wv4.z);
            o.w = f2b(v[i].w * sc * wv4.w);
            *(ushort4*)(outb + (size_t)row * DMODEL + c) = o;
            xs[wv][c + 0] = b2f(o.x); xs[wv][c + 1] = b2f(o.y);
            xs[wv][c + 2] = b2f(o.z); xs[wv][c + 3] = b2f(o.w);
        }
        __syncthreads();
        // dt phase: thread group of 4 per (dir,h); float4 weight loads (64 iters)
        int h2 = tid >> 2, part = tid & 3;
        int dir = h2 >> 5, h = h2 & 31;
        const float* wd = (dir ? b_in_w : f_in_w) + (size_t)(DPROJ2 + h) * DMODEL;
        float a0 = 0.f, a1 = 0.f, a2 = 0.f, a3 = 0.f;
        #pragma unroll 4
        for (int kk = 0; kk < 64; ++kk) {
            int k = part * 4 + (kk << 4);
            float4 wv4 = *(const float4*)(wd + k);
            a0 += xs[0][k] * wv4.x + xs[0][k + 1] * wv4.y + xs[0][k + 2] * wv4.z + xs[0][k + 3] * wv4.w;
            a1 += xs[1][k] * wv4.x + xs[1][k + 1] * wv4.y + xs[1][k + 2] * wv4.z + xs[1][k + 3] * wv4.w;
            a2 += xs[2][k] * wv4.x + xs[2][k + 1] * wv4.y + xs[2][k + 2] * wv4.z + xs[2][k + 3] * wv4.w;
            a3 += xs[3][k] * wv4.x + xs[3][k + 1] * wv4.y + xs[3][k + 2] * wv4.z + xs[3][k + 3] * wv4.w;
        }
        #pragma unroll
        for (int off = 2; off > 0; off >>= 1) {
            a0 += __shfl_down(a0, off, 4); a1 += __shfl_down(a1, off, 4);
            a2 += __shfl_down(a2, off, 4); a3 += __shfl_down(a3, off, 4);
        }
        if (part == 0) {
            float bsh = dir ? dtb_b[h] : dtb_f[h];
            float* dtp = dt + (size_t)dir * T * NH;
            float vv[4] = {a0, a1, a2, a3};
            #pragma unroll
            for (int rr = 0; rr < 4; ++rr) {
                int rg = r0 + rr;
                if (dir) rg = flipseq(rg);
                float vvv = vv[rr] + bsh;
                dtp[(size_t)rg * NH + h] = (vvv > 20.f) ? vvv : log1pf(expf(vvv));
            }
        }
        return;
    }
    // ---- weight prep path ----
    int bid = bid0 - 1024;
    if (bid < F2B_BLOCKS) {
        size_t i = ((size_t)bid * 256 + tid) * 4;
        const float* s; u16* d; size_t off;
        if (i < 2 * N_INW) {
            int dir = i >= N_INW;
            off = i - (size_t)dir * N_INW;
            s = dir ? b_in_w : f_in_w; d = d_inwb + (size_t)dir * N_INW;
        } else {
            off = i - 2 * N_INW;
            if (off >= N_OUTW) return;
            s = out_w_blk; d = d_owbb;
        }
        float4 v = *(const float4*)(s + off);
        ushort4 o;
        o.x = f2b(v.x); o.y = f2b(v.y); o.z = f2b(v.z); o.w = f2b(v.w);
        *(ushort4*)(d + off) = o;
        return;
    }
    int b2 = bid - F2B_BLOCKS;
    int dir = b2 >> 9;
    int rem = b2 & 511;
    int c0 = (rem & 31) * 64, e0 = (rem >> 5) * 64;
    const float* src = dir ? b_out_w : f_out_w;
    u16* d = d_fowT + (size_t)dir * N_OUTW;
    for (int i = tid; i < 64 * 16; i += 256) {
        int el = i >> 4, c4 = (i & 15) * 4;
        float4 v = *(const float4*)(src + (size_t)(e0 + el) * DINNER + c0 + c4);
        t[c4 + 0][el] = f2b(v.x); t[c4 + 1][el] = f2b(v.y);
        t[c4 + 2][el] = f2b(v.z); t[c4 + 3][el] = f2b(v.w);
    }
    __syncthreads();
    for (int i = tid; i < 64 * 16; i += 256) {
        int cl = i >> 4, e4 = (i & 15) * 4;
        ushort4 o;
        o.x = t[cl][e4]; o.y = t[cl][e4 + 1]; o.z = t[cl][e4 + 2]; o.w = t[cl][e4 + 3];
        *(ushort4*)(d + (size_t)(c0 + cl) * DMODEL + e0 + e4) = o;
    }
}

// ---------------- in-proj main: 256x256 tile, BK=64, 8-wave 8-phase pipelined MFMA GEMM ----------------
__global__ __launch_bounds__(512, 2) void k_mm_in8(
    const u16* __restrict__ A, const u16* __restrict__ W0,
    u16* __restrict__ zb0, u16* __restrict__ xbcraw0)
{
    __shared__ u16 lds_[8 * 8192];   // 128 KiB: [dbuf(2)][A/B(2)][half(2)] x 128x64 bf16
    int dir = blockIdx.z;
    const u16* W = W0 + (size_t)dir * N_INW;

    int f = blockIdx.x + (blockIdx.y << 4);   // 0..255 within dir; xcd = f & 7
    int xcd = f & 7;
    int jj = f >> 3;                          // 0..31
    int m0 = (jj >> 1) * 256;
    int n0 = ((xcd << 1) | (jj & 1)) * 256;

    u16* Cout; int ldcc, nbase;
    if (n0 < DINNER) {
        Cout = zb0 + (size_t)dir * T * DINNER;
        ldcc = DINNER;
        nbase = n0;
    } else {
        Cout = xbcraw0 + (size_t)dir * T * CONVCH;
        ldcc = CONVCH;
        nbase = n0 - DINNER;
    }

    int tid = threadIdx.x;
    int lane = tid & 63;
    int w = tid >> 6;          // 0..7
    int wm = w >> 2;           // 0..1  (M half: 128 rows)
    int wn = w & 3;            // 0..3  (N slice: 64 cols)
    int l15 = lane & 15;
    int gsw0 = (((lane >> 4) ^ (lane & 7)) << 3);        // ks = 0
    int gsw1 = (((4 + (lane >> 4)) ^ (lane & 7)) << 3);  // ks = 1

    const u16* pA[2][2];
    const u16* pB[2][2];
    int swz = ((lane & 7) ^ (lane >> 3)) << 3;   // pre-swizzled global column granule
    #pragma unroll
    for (int h = 0; h < 2; ++h)
        #pragma unroll
        for (int c = 0; c < 2; ++c) {
            int rl = (w * 2 + c) * 8 + (lane >> 3);     // 0..127 within half
            int grow = m0 + h * 128 + rl;
            if (dir) grow = flipseq(grow);
            pA[h][c] = A + (size_t)grow * DMODEL + swz;
            pB[h][c] = W + (size_t)(n0 + h * 128 + rl) * DMODEL + swz;
        }
    int dst0 = (w * 2 + 0) * 512 + lane * 8;
    int dst1 = (w * 2 + 1) * 512 + lane * 8;

#define STAGE_A(t_, h_) do { \
        gload16(pA[h_][0] + (t_) * 64, lds_ + (((t_) & 1) * 4 + (h_)) * 8192 + dst0); \
        gload16(pA[h_][1] + (t_) * 64, lds_ + (((t_) & 1) * 4 + (h_)) * 8192 + dst1); \
    } while (0)
#define STAGE_B(t_, h_) do { \
        gload16(pB[h_][0] + (t_) * 64, lds_ + (((t_) & 1) * 4 + 2 + (h_)) * 8192 + dst0); \
        gload16(pB[h_][1] + (t_) * 64, lds_ + (((t_) & 1) * 4 + 2 + (h_)) * 8192 + dst1); \
    } while (0)

    f32x4 acc[8][4] = {};
    bf16x8 bfv[4][2];

    STAGE_A(0, 0); STAGE_A(0, 1); STAGE_B(0, 0); STAGE_B(0, 1);
    FENCE;
    STAGE_B(1, 0); STAGE_B(1, 1);
    asm volatile("s_waitcnt vmcnt(4)" ::: "memory");
    __builtin_amdgcn_s_barrier();
    FENCE;

    for (int kt = 0; kt < 16; ++kt) {
        int d = kt & 1;
        const u16* Ab = lds_ + (d * 4 + wm) * 8192;
        const u16* Bb = lds_ + (d * 4 + 2 + (wn >> 1)) * 8192;
        int nrow0 = (wn & 1) * 64;
        #pragma unroll
        for (int q = 0; q < 4; ++q) {
            if (q == 0) {
                #pragma unroll
                for (int j = 0; j < 4; ++j) {
                    const u16* bp = Bb + (nrow0 + j * 16 + l15) * 64;
                    bfv[j][0] = *(const bf16x8*)(bp + gsw0);
                    bfv[j][1] = *(const bf16x8*)(bp + gsw1);
                }
            }
            const u16* ap0 = Ab + ((q * 2 + 0) * 16 + l15) * 64;
            const u16* ap1 = Ab + ((q * 2 + 1) * 16 + l15) * 64;
            bf16x8 a0k0 = *(const bf16x8*)(ap0 + gsw0);
            bf16x8 a0k1 = *(const bf16x8*)(ap0 + gsw1);
            bf16x8 a1k0 = *(const bf16x8*)(ap1 + gsw0);
            bf16x8 a1k1 = *(const bf16x8*)(ap1 + gsw1);
            if (q == 0)      { if (kt < 15) STAGE_A(kt + 1, 0); }
            else if (q == 1) { if (kt < 15) STAGE_A(kt + 1, 1); }
            else if (q == 2) { if (kt < 14) STAGE_B(kt + 2, 0); }
            else             { if (kt < 14) STAGE_B(kt + 2, 1); }
            FENCE;
            __builtin_amdgcn_s_barrier();
            asm volatile("s_waitcnt lgkmcnt(0)" ::: "memory");
            __builtin_amdgcn_s_setprio(1);
            #pragma unroll
            for (int j = 0; j < 4; ++j) {
                acc[q * 2 + 0][j] = __builtin_amdgcn_mfma_f32_16x16x32_bf16(a0k0, bfv[j][0], acc[q * 2 + 0][j], 0, 0, 0);
                acc[q * 2 + 0][j] = __builtin_amdgcn_mfma_f32_16x16x32_bf16(a0k1, bfv[j][1], acc[q * 2 + 0][j], 0, 0, 0);
                acc[q * 2 + 1][j] = __builtin_amdgcn_mfma_f32_16x16x32_bf16(a1k0, bfv[j][0], acc[q * 2 + 1][j], 0, 0, 0);
                acc[q * 2 + 1][j] = __builtin_amdgcn_mfma_f32_16x16x32_bf16(a1k1, bfv[j][1], acc[q * 2 + 1][j], 0, 0, 0);
            }
            __builtin_amdgcn_s_setprio(0);
            if (q == 3) {
                if (kt < 14)       asm volatile("s_waitcnt vmcnt(4)" ::: "memory");
                else if (kt == 14) asm volatile("s_waitcnt vmcnt(0)" ::: "memory");
            }
            FENCE;
            __builtin_amdgcn_s_barrier();
            FENCE;
        }
    }
#undef STAGE_A
#undef STAGE_B

    int rb = m0 + wm * 128 + ((lane >> 4) << 2);
    int cb = nbase + wn * 64 + l15;
    #pragma unroll
    for (int i = 0; i < 8; ++i)
        #pragma unroll
        for (int j = 0; j < 4; ++j)
            #pragma unroll
            for (int r = 0; r < 4; ++r)
                Cout[(size_t)(rb + i * 16 + r) * ldcc + cb + j * 16] = f2b(acc[i][j][r]);
}

// ---------------- in-proj cleanup: bf16 MFMA GEMM 128x128, BK=64, z = dir (proven m97-structure) ----------------
__global__ __launch_bounds__(256, 4) void k_mm_in(
    const u16* __restrict__ A, const u16* __restrict__ W0,
    u16* __restrict__ zb0, u16* __restrict__ xbcraw0, int ny0)
{
    const int K = DMODEL;
    int dir = blockIdx.z;
    const u16* W = W0 + (size_t)dir * N_INW;
    int m0 = blockIdx.x * 128, n0 = (blockIdx.y + ny0) * 128;

    u16* Cout;
    int ldcc, nbase;
    if (n0 < DINNER) {
        Cout = zb0 + (size_t)dir * T * DINNER;
        ldcc = DINNER;
        nbase = n0;
    } else {
        Cout = xbcraw0 + (size_t)dir * T * CONVCH;
        ldcc = CONVCH;
        nbase = n0 - DINNER;
    }

    __shared__ u16 As[2 * 128 * 32];
    __shared__ u16 Bs[2 * 128 * 32];
    int tid = threadIdx.x;
    int lane = tid & 63;
    int wrow = ((tid >> 6) & 1) * 64, wcol = (tid >> 7) * 64;

    int srow = tid >> 2, skof = (tid & 3) * 8;
    int ar1 = m0 + srow, ar2 = ar1 + 64;
    if (dir) { ar1 = flipseq(ar1); ar2 = flipseq(ar2); }
    const u16* ga1 = A + (size_t)ar1 * K + skof;
    const u16* ga2 = A + (size_t)ar2 * K + skof;
    const u16* gb1 = W + (size_t)(n0 + srow) * K + skof;
    const u16* gb2 = gb1 + (size_t)64 * K;
    u16* la1 = As + tid * 8;
    u16* la2 = As + 2048 + tid * 8;
    u16* lb1 = Bs + tid * 8;
    u16* lb2 = Bs + 2048 + tid * 8;

    int aoff[4], boff[4];
    #pragma unroll
    for (int i = 0; i < 4; ++i) {
        aoff[i] = (wrow + i * 16 + (lane & 15)) * 32 + ((lane >> 4) * 8);
        boff[i] = (wcol + i * 16 + (lane & 15)) * 32 + ((lane >> 4) * 8);
    }

    f32x4 acc[4][4] = {};
    for (int kt = 0; kt < K; kt += 64) {
        gload16(ga1, la1);        gload16(ga2, la2);
        gload16(ga1 + 32, la1 + 4096); gload16(ga2 + 32, la2 + 4096);
        gload16(gb1, lb1);        gload16(gb2, lb2);
        gload16(gb1 + 32, lb1 + 4096); gload16(gb2 + 32, lb2 + 4096);
        ga1 += 64; ga2 += 64; gb1 += 64; gb2 += 64;
        __syncthreads();
        #pragma unroll
        for (int ks = 0; ks < 2; ++ks) {
            bf16x8 af[4], bfv[4];
            #pragma unroll
            for (int i = 0; i < 4; ++i) af[i] = *(const bf16x8*)(As + ks * 4096 + aoff[i]);
            #pragma unroll
            for (int j = 0; j < 4; ++j) bfv[j] = *(const bf16x8*)(Bs + ks * 4096 + boff[j]);
            #pragma unroll
            for (int i = 0; i < 4; ++i)
                #pragma unroll
                for (int j = 0; j < 4; ++j)
                    acc[i][j] = __builtin_amdgcn_mfma_f32_16x16x32_bf16(af[i], bfv[j], acc[i][j], 0, 0, 0);
        }
        __syncthreads();
    }

    int rbase = m0 + wrow + ((lane >> 4) << 2);
    int cbase = nbase + wcol + (lane & 15);
    #pragma unroll
    for (int i = 0; i < 4; ++i)
        #pragma unroll
        for (int j = 0; j < 4; ++j)
            #pragma unroll
            for (int r = 0; r < 4; ++r)
                Cout[(size_t)(rbase + i * 16 + r) * ldcc + cbase + j * 16] = f2b(acc[i][j][r]);
}

// ---------------- weight-fold GEMM: Mcomb_dir = owbb[:, dir*1024:] @ fowT_dir^T ----------------
__global__ __launch_bounds__(256) void k_mm64(
    const u16* __restrict__ A0, const u16* __restrict__ W0,
    u16* __restrict__ Cb)
{
    int bid = blockIdx.x;
    int xcd = bid & 7;
    int j9 = bid >> 3;               // 0..63
    int dir = j9 >> 5;
    int m0 = xcd * 128;
    int n0 = (j9 & 31) * 64;
    const u16* A = A0 + dir * DMODEL;                 // column offset in 2048-wide rows
    const u16* W = W0 + (size_t)dir * N_OUTW;

    __shared__ u16 As[2 * 128 * 32];   // 8192 u16
    __shared__ u16 Bs[2 * 64 * 32];    // 4096 u16
    int tid = threadIdx.x;
    int lane = tid & 63;
    int w = tid >> 6;
    int wrow = (w & 1) * 64, wcol = (w >> 1) * 32;

    int srow = tid >> 2, skof = (tid & 3) * 8;
    const u16* ga1 = A + (size_t)(m0 + srow) * 2048 + skof;
    const u16* ga2 = A + (size_t)(m0 + 64 + srow) * 2048 + skof;
    const u16* gb  = W + (size_t)(n0 + srow) * DMODEL + skof;
    u16* la1 = As + tid * 8;
    u16* la2 = As + 2048 + tid * 8;
    u16* lb  = Bs + tid * 8;

    int aoff[4], boff[2];
    #pragma unroll
    for (int i = 0; i < 4; ++i)
        aoff[i] = (wrow + i * 16 + (lane & 15)) * 32 + ((lane >> 4) * 8);
    #pragma unroll
    for (int j = 0; j < 2; ++j)
        boff[j] = (wcol + j * 16 + (lane & 15)) * 32 + ((lane >> 4) * 8);

    f32x4 acc[4][2] = {};
    for (int kt = 0; kt < DMODEL; kt += 64) {
        gload16(ga1, la1); gload16(ga1 + 32, la1 + 4096);
        gload16(ga2, la2); gload16(ga2 + 32, la2 + 4096);
        gload16(gb, lb);   gload16(gb + 32, lb + 2048);
        ga1 += 64; ga2 += 64; gb += 64;
        __syncthreads();
        #pragma unroll
        for (int ks = 0; ks < 2; ++ks) {
            bf16x8 af[4], bfv[2];
            #pragma unroll
            for (int i = 0; i < 4; ++i) af[i] = *(const bf16x8*)(As + ks * 4096 + aoff[i]);
            #pragma unroll
            for (int j = 0; j < 2; ++j) bfv[j] = *(const bf16x8*)(Bs + ks * 2048 + boff[j]);
            #pragma unroll
            for (int i = 0; i < 4; ++i)
                #pragma unroll
                for (int j = 0; j < 2; ++j)
                    acc[i][j] = __builtin_amdgcn_mfma_f32_16x16x32_bf16(af[i], bfv[j], acc[i][j], 0, 0, 0);
        }
        __syncthreads();
    }

    int rbase = m0 + wrow + ((lane >> 4) << 2);
    int cbase = n0 + wcol + (lane & 15);
    #pragma unroll
    for (int i = 0; i < 4; ++i)
        #pragma unroll
        for (int j = 0; j < 2; ++j)
            #pragma unroll
            for (int r = 0; r < 4; ++r)
                Cb[(size_t)(rbase + i * 16 + r) * 4096 + dir * 2048 + cbase + j * 16] = f2b(acc[i][j][r]);
}

// ---------------- final fused GEMM: 8-phase pipelined clone of k_mm_in8 ----------------
__global__ __launch_bounds__(512, 2) void k_mm_fin8(
    const u16* __restrict__ A1, const u16* __restrict__ A2,
    const u16* __restrict__ W,      // Mcomb: 1024 x 4096 (Mf | Mb), k-contig
    float* __restrict__ out, const float* __restrict__ bias,
    const float* __restrict__ resid)
{
    __shared__ u16 lds_[8 * 8192];   // 128 KiB: [dbuf(2)][{A1,A2,B1,B2}] x 128x64 bf16
    int bid = blockIdx.x;
    int xcd = bid & 7;
    int j9 = bid >> 3;                  // 0..31
    int m0 = (xcd * 4 + (j9 & 3)) * 128;
    int n0 = (j9 >> 2) * 128;
    int tid = threadIdx.x;
    int lane = tid & 63;
    int w = tid >> 6;          // 0..7
    int wm = w >> 2;           // 0..1  (64-row half)
    int wn = w & 3;            // 0..3  (32-col slice)
    int l15 = lane & 15;
    int gsw0 = (((lane >> 4) ^ (lane & 7)) << 3);
    int gsw1 = (((4 + (lane >> 4)) ^ (lane & 7)) << 3);

    const u16* p[4][2];
    int swz = ((lane & 7) ^ (lane >> 3)) << 3;
    #pragma unroll
    for (int c = 0; c < 2; ++c) {
        int rl = (w * 2 + c) * 8 + (lane >> 3);     // 0..127
        p[0][c] = A1 + (size_t)(m0 + rl) * DINNER + swz;
        p[1][c] = A2 + (size_t)flipseq(m0 + rl) * DINNER + swz;
        p[2][c] = W + (size_t)(n0 + rl) * 4096 + swz;
        p[3][c] = p[2][c] + 2048;
    }
    int dst0 = (w * 2 + 0) * 512 + lane * 8;
    int dst1 = (w * 2 + 1) * 512 + lane * 8;

#define STG(t_, s_) do { \
        gload16(p[s_][0] + (t_) * 64, lds_ + (((t_) & 1) * 4 + (s_)) * 8192 + dst0); \
        gload16(p[s_][1] + (t_) * 64, lds_ + (((t_) & 1) * 4 + (s_)) * 8192 + dst1); \
    } while (0)

    f32x4 acc[4][2] = {};
    bf16x8 bf1[2][2], bf2[2][2];

    // prologue: tile0 all 4 half-tiles + tile1 B halves in flight
    STG(0, 0); STG(0, 1); STG(0, 2); STG(0, 3);
    FENCE;
    STG(1, 2); STG(1, 3);
    asm volatile("s_waitcnt vmcnt(4)" ::: "memory");
    __builtin_amdgcn_s_barrier();
    FENCE;

    for (int kt = 0; kt < 32; ++kt) {
        int d = kt & 1;
        const u16* A1b = lds_ + (d * 4 + 0) * 8192;
        const u16* A2b = lds_ + (d * 4 + 1) * 8192;
        const u16* B1b = lds_ + (d * 4 + 2) * 8192;
        const u16* B2b = lds_ + (d * 4 + 3) * 8192;
        #pragma unroll
        for (int ph = 0; ph < 2; ++ph) {
            if (ph == 0) {
                #pragma unroll
                for (int j = 0; j < 2; ++j) {
                    const u16* bp1 = B1b + (wn * 32 + j * 16 + l15) * 64;
                    const u16* bp2 = B2b + (wn * 32 + j * 16 + l15) * 64;
                    bf1[j][0] = *(const bf16x8*)(bp1 + gsw0);
                    bf1[j][1] = *(const bf16x8*)(bp1 + gsw1);
                    bf2[j][0] = *(const bf16x8*)(bp2 + gsw0);
                    bf2[j][1] = *(const bf16x8*)(bp2 + gsw1);
                }
            }
            bf16x8 a1[2][2], a2[2][2];
            #pragma unroll
            for (int i = 0; i < 2; ++i) {
                int ro = (wm * 64 + (ph * 2 + i) * 16 + l15) * 64;
                a1[i][0] = *(const bf16x8*)(A1b + ro + gsw0);
                a1[i][1] = *(const bf16x8*)(A1b + ro + gsw1);
                a2[i][0] = *(const bf16x8*)(A2b + ro + gsw0);
                a2[i][1] = *(const bf16x8*)(A2b + ro + gsw1);
            }
            if (ph == 0) { if (kt < 31) { STG(kt + 1, 0); STG(kt + 1, 1); } }
            else         { if (kt < 30) { STG(kt + 2, 2); STG(kt + 2, 3); } }
            FENCE;
            __builtin_amdgcn_s_barrier();
            asm volatile("s_waitcnt lgkmcnt(0)" ::: "memory");
            __builtin_amdgcn_s_setprio(1);
            #pragma unroll
            for (int i = 0; i < 2; ++i)
                #pragma unroll
                for (int j = 0; j < 2; ++j) {
                    int q = ph * 2 + i;
                    acc[q][j] = __builtin_amdgcn_mfma_f32_16x16x32_bf16(a1[i][0], bf1[j][0], acc[q][j], 0, 0, 0);
                    acc[q][j] = __builtin_amdgcn_mfma_f32_16x16x32_bf16(a1[i][1], bf1[j][1], acc[q][j], 0, 0, 0);
                    acc[q][j] = __builtin_amdgcn_mfma_f32_16x16x32_bf16(a2[i][0], bf2[j][0], acc[q][j], 0, 0, 0);
                    acc[q][j] = __builtin_amdgcn_mfma_f32_16x16x32_bf16(a2[i][1], bf2[j][1], acc[q][j], 0, 0, 0);
                }
            __builtin_amdgcn_s_setprio(0);
            if (ph == 1) {
                if (kt < 30)       asm volatile("s_waitcnt vmcnt(4)" ::: "memory");
                else if (kt == 30) asm volatile("s_waitcnt vmcnt(0)" ::: "memory");
            }
            FENCE;
            __builtin_amdgcn_s_barrier();
            FENCE;
        }
    }
#undef STG

    int rb = m0 + wm * 64 + ((lane >> 4) << 2);
    int cb = n0 + wn * 32 + l15;
    #pragma unroll
    for (int i = 0; i < 4; ++i)
        #pragma unroll
        for (int j = 0; j < 2; ++j)
            #pragma unroll
            for (int r = 0; r < 4; ++r) {
                int row = rb + i * 16 + r, col = cb + j * 16;
                out[(size_t)row * DMODEL + col] =
                    acc[i][j][r] + bias[col] + resid[(size_t)row * DMODEL + col];
            }
}

// ---------------- conv4 + silu, 4 rows x 8 ch per thread (sliding window); z = dir ----------------
__global__ void k_conv(const u16* __restrict__ xraw0,
                       const float* __restrict__ cw_f, const float* __restrict__ cw_b,
                       const float* __restrict__ cb_f, const float* __restrict__ cb_b,
                       const float* __restrict__ dt0,
                       u16* __restrict__ xbcb0, u16* __restrict__ xdtb0)
{
    int dir = blockIdx.z;
    const u16* xraw = xraw0 + (size_t)dir * T * CONVCH;
    const float* cw = dir ? cw_b : cw_f;
    const float* cb = dir ? cb_b : cb_f;
    const float* dt = dt0 + (size_t)dir * T * NH;
    u16* xbcb = xbcb0 + (size_t)dir * T * CONVCH;
    u16* xdtb = xdtb0 + (size_t)dir * T * DINNER;

    int idx = blockIdx.x * blockDim.x + threadIdx.x;
    if (idx >= (T / 4) * (CONVCH / 8)) return;
    int r4 = idx / (CONVCH / 8);
    int c8 = (idx - r4 * (CONVCH / 8)) * 8;
    int r0 = r4 * 4;                  // 4 rows, all within one sequence (SEQL % 4 == 0)
    int t0 = r0 & (SEQL - 1);

    float4 cwv[8];
    #pragma unroll
    for (int j = 0; j < 8; ++j) cwv[j] = *(const float4*)(cw + (size_t)(c8 + j) * 4);
    float acc[4][8];
    {
        float4 c0 = *(const float4*)(cb + c8);
        float4 c1 = *(const float4*)(cb + c8 + 4);
        #pragma unroll
        for (int i = 0; i < 4; ++i) {
            acc[i][0] = c0.x; acc[i][1] = c0.y; acc[i][2] = c0.z; acc[i][3] = c0.w;
            acc[i][4] = c1.x; acc[i][5] = c1.y; acc[i][6] = c1.z; acc[i][7] = c1.w;
        }
    }
    // source rows s = 0..6 map to global row r0 - 3 + s; output i uses tap j = s - i
    #pragma unroll
    for (int s = 0; s < 7; ++s) {
        int tt = t0 - 3 + s;
        if (tt < 0) continue;        // pre-sequence padding (zero)
        const u16* src = xraw + (size_t)(r0 - 3 + s) * CONVCH + c8;
        ushort4 v0 = *(const ushort4*)src;
        ushort4 v1 = *(const ushort4*)(src + 4);
        float xv[8] = {b2f(v0.x), b2f(v0.y), b2f(v0.z), b2f(v0.w),
                       b2f(v1.x), b2f(v1.y), b2f(v1.z), b2f(v1.w)};
        #pragma unroll
        for (int i = 0; i < 4; ++i) {
            if (i <= s && i >= s - 3) {     // compile-time after unroll
                const int j = s - i;        // tap index 0..3
                #pragma unroll
                for (int ch = 0; ch < 8; ++ch) {
                    float wv = (j == 0) ? cwv[ch].x : (j == 1) ? cwv[ch].y
                             : (j == 2) ? cwv[ch].z : cwv[ch].w;
                    acc[i][ch] += xv[ch] * wv;
                }
            }
        }
    }
    #pragma unroll
    for (int i = 0; i < 4; ++i) {
        int r = r0 + i;
        float sgl[8];
        #pragma unroll
        for (int ch = 0; ch < 8; ++ch) sgl[ch] = acc[i][ch] / (1.f + __expf(-acc[i][ch]));
        ushort4 o0, o1;
        o0.x = f2b(sgl[0]); o0.y = f2b(sgl[1]); o0.z = f2b(sgl[2]); o0.w = f2b(sgl[3]);
        o1.x = f2b(sgl[4]); o1.y = f2b(sgl[5]); o1.z = f2b(sgl[6]); o1.w = f2b(sgl[7]);
        *(ushort4*)(xbcb + (size_t)r * CONVCH + c8) = o0;
        *(ushort4*)(xbcb + (size_t)r * CONVCH + c8 + 4) = o1;
        if (c8 < DINNER) {
            float dv = dt[(size_t)r * NH + (c8 >> 6)];
            ushort4 d0, d1;
            d0.x = f2b(sgl[0] * dv); d0.y = f2b(sgl[1] * dv);
            d0.z = f2b(sgl[2] * dv); d0.w = f2b(sgl[3] * dv);
            d1.x = f2b(sgl[4] * dv); d1.y = f2b(sgl[5] * dv);
            d1.z = f2b(sgl[6] * dv); d1.w = f2b(sgl[7] * dv);
            *(ushort4*)(xdtb + (size_t)r * DINNER + c8) = d0;
            *(ushort4*)(xdtb + (size_t)r * DINNER + c8 + 4) = d1;
        }
    }
}

#define LDW 136
// ---------------- states + inline acs: cumsum, st = (X*dt)^T @ (B*dec); z = dir ----------------
// Scan via per-wave __shfl_up inclusive scan (2 barriers) instead of 14-barrier Hillis-Steele.
__global__ __launch_bounds__(256) void k_states(
    const u16* __restrict__ xbcb0, const u16* __restrict__ xdtb0,
    const float* __restrict__ dt0,
    const float* __restrict__ Alog_f, const float* __restrict__ Alog_b,
    float* __restrict__ acs0, float* __restrict__ cd0, u16* __restrict__ st0)
{
    int dir = blockIdx.z;
    const u16* xbcb = xbcb0 + (size_t)dir * T * CONVCH;
    const u16* xdtb = xdtb0 + (size_t)dir * T * DINNER;
    const float* dt = dt0 + (size_t)dir * T * NH;
    const float* A_log = dir ? Alog_b : Alog_f;
    float* acs = acs0 + (size_t)dir * BATCH * NH * NCH * CHUNK;
    float* cd = cd0 + (size_t)dir * BATCH * NH * NCH;
    u16* st = st0 + (size_t)dir * N_ST;

    __shared__ u16 Bt[128 * LDW];
    __shared__ u16 Xt[64 * LDW];
    __shared__ float cs[128];
    __shared__ float dec_s[128];
    int tid = threadIdx.x;
    int lane = tid & 63;
    int w = tid >> 6;
    int h = blockIdx.x & 31;
    int bc = blockIdx.x >> 5;
    int c = bc & 15, b = bc >> 4;
    int row0 = b * SEQL + c * CHUNK;

    float val = 0.f;
    if (tid < 128) {
        float Ah = -expf(A_log[h]);
        val = Ah * dt[(size_t)(row0 + tid) * NH + h];
    }
    for (int i = tid; i < 128 * 16; i += 256) {
        int l = i >> 4, pg = (i & 15) * 4;
        ushort4 v = *(const ushort4*)(xdtb + (size_t)(row0 + l) * DINNER + h * HD + pg);
        Xt[(pg + 0) * LDW + l] = v.x; Xt[(pg + 1) * LDW + l] = v.y;
        Xt[(pg + 2) * LDW + l] = v.z; Xt[(pg + 3) * LDW + l] = v.w;
    }
    // per-wave inclusive scan (waves 0,1 carry rows 0-63 / 64-127)
    #pragma unroll
    for (int off = 1; off < 64; off <<= 1) {
        float n = __shfl_up(val, off);
        if (lane >= off) val += n;
    }
    if (tid < 128) cs[tid] = val;
    __syncthreads();                       // also covers Xt staging
    if (tid >= 64 && tid < 128) {
        val += cs[63];
        cs[tid] = val;
    }
    __syncthreads();
    size_t abase = ((size_t)(b * NH + h) * NCH + c) << 7;
    if (tid < 128) acs[abase + tid] = cs[tid];
    float a_last = cs[127];
    if (tid == 127) cd[(b * NH + h) * NCH + c] = expf(a_last);
    if (tid < 128) dec_s[tid] = __expf(a_last - cs[tid]);
    __syncthreads();
    for (int i = tid; i < 128 * 32; i += 256) {
        int l = i >> 5, ng = (i & 31) * 4;
        ushort4 v = *(const ushort4*)(xbcb + (size_t)(row0 + l) * CONVCH + DINNER + ng);
        float d = dec_s[l];
        Bt[(ng + 0) * LDW + l] = f2b(b2f(v.x) * d);
        Bt[(ng + 1) * LDW + l] = f2b(b2f(v.y) * d);
        Bt[(ng + 2) * LDW + l] = f2b(b2f(v.z) * d);
        Bt[(ng + 3) * LDW + l] = f2b(b2f(v.w) * d);
    }
    __syncthreads();
    f32x4 tacc[8] = {};
    for (int kk = 0; kk < 4; ++kk) {
        bf16x8 afs = *(const bf16x8*)(Xt + (w * 16 + (lane & 15)) * LDW
                                      + kk * 32 + (lane >> 4) * 8);
        #pragma unroll
        for (int j = 0; j < 8; ++j) {
            bf16x8 bfs = *(const bf16x8*)(Bt + (j * 16 + (lane & 15)) * LDW
                                          + kk * 32 + (lane >> 4) * 8);
            tacc[j] = __builtin_amdgcn_mfma_f32_16x16x32_bf16(afs, bfs, tacc[j], 0, 0, 0);
        }
    }
    size_t sb = (size_t)blockIdx.x * (HD * DSTATE);
    #pragma unroll
    for (int j = 0; j < 8; ++j)
        #pragma unroll
        for (int r = 0; r < 4; ++r) {
            int p = w * 16 + (lane >> 4) * 4 + r;
            int n = j * 16 + (lane & 15);
            st[sb + (size_t)p * DSTATE + n] = f2b(tacc[j][r]);
        }
}

// ---------------- inter-chunk scan (in place, bf16), both dirs ----------------
__global__ void k_scan(u16* __restrict__ st0, const float* __restrict__ cd0)
{
    int i = blockIdx.x * blockDim.x + threadIdx.x;
    if (i >= 2 * BATCH * NH * HD * DSTATE) return;
    int dir = i >> 19;
    int j = i & ((1 << 19) - 1);
    u16* st = st0 + (size_t)dir * N_ST;
    const float* cd = cd0 + (size_t)dir * BATCH * NH * NCH;
    int n = j & 127;
    int rest = j >> 7;
    int p = rest & 63; rest >>= 6;
    int h = rest & 31;
    int b = rest >> 5;
    float s = 0.f;
    for (int c = 0; c < NCH; ++c) {
        size_t idx = ((size_t)((b * NCH + c) * NH + h) * HD + p) * DSTATE + n;
        float v = b2f(st[idx]);
        st[idx] = f2b(s);
        s = s * cd[(b * NH + h) * NCH + c] + v;
    }
}

// ---------------- fused per-(b,c,h): Y_diag + Y_off + xh*D -> y (single write); z = dir ----------------
// oacc B-operand (prev state) read DIRECTLY from global (row-major [p][128] matches the
// MFMA fragment) -- removes the prev->LDS staging phase and 2 of 5 barriers. Bit-identical.
__global__ __launch_bounds__(256) void k_chunk(
    const u16* __restrict__ xbcb0, const u16* __restrict__ xdtb0,
    const float* __restrict__ acs0, const u16* __restrict__ prev0,
    const float* __restrict__ D_f, const float* __restrict__ D_b,
    u16* __restrict__ y0)
{
    int dir = blockIdx.z;
    const u16* xbcb = xbcb0 + (size_t)dir * T * CONVCH;
    const u16* xdtb = xdtb0 + (size_t)dir * T * DINNER;
    const float* acs = acs0 + (size_t)dir * BATCH * NH * NCH * CHUNK;
    const u16* prev = prev0 + (size_t)dir * N_ST;
    const float* Dp = dir ? D_b : D_f;
    u16* y = y0 + (size_t)dir * T * DINNER;

    __shared__ u16 S0[128 * LDW];
    __shared__ u16 Xt[64 * LDW];
    __shared__ float acs_s[128];
    int tid = threadIdx.x;
    int lane = tid & 63;
    int w = tid >> 6;
    int h = blockIdx.x & 31;
    int bc = blockIdx.x >> 5;
    int c = bc & 15, b = bc >> 4;
    int row0 = b * SEQL + c * CHUNK;

    if (tid < 128)
        acs_s[tid] = acs[(((size_t)(b * NH + h) * NCH + c) << 7) + tid];
    for (int i = tid; i < 128 * 16; i += 256) {
        int s = i >> 4, m8 = (i & 15) * 8;
        *(uint4*)(S0 + s * LDW + m8) =
            *(const uint4*)(xbcb + (size_t)(row0 + s) * CONVCH + DINNER + m8);
    }
    for (int i = tid; i < 128 * 16; i += 256) {
        int l = i >> 4, pg = (i & 15) * 4;
        ushort4 v = *(const ushort4*)(xdtb + (size_t)(row0 + l) * DINNER + h * HD + pg);
        Xt[(pg + 0) * LDW + l] = v.x; Xt[(pg + 1) * LDW + l] = v.y;
        Xt[(pg + 2) * LDW + l] = v.z; Xt[(pg + 3) * LDW + l] = v.w;
    }
    __syncthreads();

    int wrow = (w & 1) * 64, wcol = (w >> 1) * 64;
    const u16* cbase = xbcb + (size_t)row0 * CONVCH + DINNER + DSTATE;
    f32x4 sacc[4][4] = {};
    for (int kk = 0; kk < 4; ++kk) {
        bf16x8 af[4], bfr[4];
        #pragma unroll
        for (int i = 0; i < 4; ++i)
            af[i] = *(const bf16x8*)(cbase + (size_t)(wrow + i * 16 + (lane & 15)) * CONVCH
                                     + kk * 32 + (lane >> 4) * 8);
        #pragma unroll
        for (int j = 0; j < 4; ++j)
            bfr[j] = *(const bf16x8*)(S0 + (wcol + j * 16 + (lane & 15)) * LDW
                                      + kk * 32 + (lane >> 4) * 8);
        #pragma unroll
        for (int i = 0; i < 4; ++i)
            #pragma unroll
            for (int j = 0; j < 4; ++j)
                if (wcol + j * 16 <= wrow + i * 16 + 15)
                    sacc[i][j] = __builtin_amdgcn_mfma_f32_16x16x32_bf16(af[i], bfr[j], sacc[i][j], 0, 0, 0);
    }
    __syncthreads();
    #pragma unroll
    for (int i = 0; i < 4; ++i)
        #pragma unroll
        for (int j = 0; j < 4; ++j) {
            int s = wcol + j * 16 + (lane & 15);
            #pragma unroll
            for (int r = 0; r < 4; ++r) {
                int l = wrow + i * 16 + (lane >> 4) * 4 + r;
                float v = (s <= l) ? sacc[i][j][r] * __expf(acs_s[l] - acs_s[s]) : 0.f;
                S0[l * LDW + s] = f2b(v);
            }
        }
    __syncthreads();
    f32x4 yacc[2][4] = {};
    for (int kk = 0; kk < 4; ++kk) {
        bf16x8 af[2], bfr[4];
        #pragma unroll
        for (int i = 0; i < 2; ++i)
            af[i] = *(const bf16x8*)(S0 + (w * 32 + i * 16 + (lane & 15)) * LDW
                                     + kk * 32 + (lane >> 4) * 8);
        #pragma unroll
        for (int j = 0; j < 4; ++j)
            bfr[j] = *(const bf16x8*)(Xt + (j * 16 + (lane & 15)) * LDW
                                      + kk * 32 + (lane >> 4) * 8);
        #pragma unroll
        for (int i = 0; i < 2; ++i)
            #pragma unroll
            for (int j = 0; j < 4; ++j)
                yacc[i][j] = __builtin_amdgcn_mfma_f32_16x16x32_bf16(af[i], bfr[j], yacc[i][j], 0, 0, 0);
    }
    // oacc: prev read directly from global (no LDS staging, no barriers needed here)
    size_t sb = (size_t)blockIdx.x * (HD * DSTATE);
    const u16* prevg = prev + sb;
    f32x4 oacc[2][4] = {};
    for (int kk = 0; kk < 4; ++kk) {
        bf16x8 af[2], bfr[4];
        #pragma unroll
        for (int i = 0; i < 2; ++i)
            af[i] = *(const bf16x8*)(cbase + (size_t)(w * 32 + i * 16 + (lane & 15)) * CONVCH
                                     + kk * 32 + (lane >> 4) * 8);
        #pragma unroll
        for (int j = 0; j < 4; ++j)
            bfr[j] = *(const bf16x8*)(prevg + (size_t)(j * 16 + (lane & 15)) * DSTATE
                                      + kk * 32 + (lane >> 4) * 8);
        #pragma unroll
        for (int i = 0; i < 2; ++i)
            #pragma unroll
            for (int j = 0; j < 4; ++j)
                oacc[i][j] = __builtin_amdgcn_mfma_f32_16x16x32_bf16(af[i], bfr[j], oacc[i][j], 0, 0, 0);
    }
    float Dh = Dp[h];
    #pragma unroll
    for (int i = 0; i < 2; ++i)
        #pragma unroll
        for (int j = 0; j < 4; ++j)
            #pragma unroll
            for (int r = 0; r < 4; ++r) {
                int l = w * 32 + i * 16 + (lane >> 4) * 4 + r;
                int p = j * 16 + (lane & 15);
                float val = yacc[i][j][r] + __expf(acs_s[l]) * oacc[i][j][r]
                          + b2f(xbcb[(size_t)(row0 + l) * CONVCH + h * HD + p]) * Dh;
                y[(size_t)(row0 + l) * DINNER + h * HD + p] = f2b(val);
            }
}

// ---------------- gated rmsnorm: wave-per-row, barrier-free; z = dir ----------------
// 4 waves/block own 4 rows; 32 elems/lane in registers; __shfl_xor butterfly reduce.
__global__ __launch_bounds__(256) void k_gate(
    const u16* __restrict__ y0, const u16* __restrict__ zb0,
    const float* __restrict__ gw_f, const float* __restrict__ gw_b,
    u16* __restrict__ out0)
{
    int dir = blockIdx.z;
    const float* gw = dir ? gw_b : gw_f;
    int lane = threadIdx.x & 63;
    int r = blockIdx.x * 4 + (threadIdx.x >> 6);
    const u16* yr = y0 + (size_t)dir * T * DINNER + (size_t)r * DINNER;
    const u16* zr = zb0 + (size_t)dir * T * DINNER + (size_t)r * DINNER;
    u16* outr = out0 + (size_t)dir * T * DINNER + (size_t)r * DINNER;

    float tv[32];
    float ss = 0.f;
    #pragma unroll
    for (int it = 0; it < 4; ++it) {
        int i = (it * 64 + lane) * 8;
        uint4 yv = *(const uint4*)(yr + i);
        uint4 zv = *(const uint4*)(zr + i);
        unsigned yu[4] = {yv.x, yv.y, yv.z, yv.w};
        unsigned zu[4] = {zv.x, zv.y, zv.z, zv.w};
        #pragma unroll
        for (int k = 0; k < 4; ++k) {
            float ya = lo16f(yu[k]), yb = hi16f(yu[k]);
            float za = lo16f(zu[k]), zc = hi16f(zu[k]);
            float ta = ya * (za / (1.f + __expf(-za)));
            float tb = yb * (zc / (1.f + __expf(-zc)));
            tv[it * 8 + k * 2 + 0] = ta;
            tv[it * 8 + k * 2 + 1] = tb;
            ss += ta * ta + tb * tb;
        }
    }
    #pragma unroll
    for (int off = 32; off > 0; off >>= 1) ss += __shfl_xor(ss, off);
    float sc = rsqrtf(ss / DINNER + EPS);
    #pragma unroll
    for (int it = 0; it < 4; ++it) {
        int i = (it * 64 + lane) * 8;
        float4 g0 = *(const float4*)(gw + i);
        float4 g1 = *(const float4*)(gw + i + 4);
        float gg[8] = {g0.x, g0.y, g0.z, g0.w, g1.x, g1.y, g1.z, g1.w};
        uint4 o;
        unsigned ov[4];
        #pragma unroll
        for (int k = 0; k < 4; ++k) {
            unsigned a = f2b(tv[it * 8 + k * 2 + 0] * sc * gg[k * 2 + 0]);
            unsigned bq = f2b(tv[it * 8 + k * 2 + 1] * sc * gg[k * 2 + 1]);
            ov[k] = a | (bq << 16);
        }
        o.x = ov[0]; o.y = ov[1]; o.z = ov[2]; o.w = ov[3];
        *(uint4*)(outr + i) = o;
    }
}

// ---------------- launch ----------------
extern "C" void kernel_launch(void* const* d_in, const int* in_sizes, int n_in,
                              void* d_out, int out_size, void* d_ws, size_t ws_size,
                              hipStream_t stream)
{
    const float* x         = (const float*)d_in[0];
    const float* norm_w    = (const float*)d_in[1];
    const float* out_w_blk = (const float*)d_in[2];
    const float* out_b_blk = (const float*)d_in[3];
    const float* f_in_w    = (const float*)d_in[4];
    const float* f_conv_w  = (const float*)d_in[5];
    const float* f_conv_b  = (const float*)d_in[6];
    const float* f_dt_bias = (const float*)d_in[7];
    const float* f_A_log   = (const float*)d_in[8];
    const float* f_D       = (const float*)d_in[9];
    const float* f_gnorm_w = (const float*)d_in[10];
    const float* f_out_w   = (const float*)d_in[11];
    const float* b_in_w    = (const float*)d_in[12];
    const float* b_conv_w  = (const float*)d_in[13];
    const float* b_conv_b  = (const float*)d_in[14];
    const float* b_dt_bias = (const float*)d_in[15];
    const float* b_A_log   = (const float*)d_in[16];
    const float* b_D       = (const float*)d_in[17];
    const float* b_gnorm_w = (const float*)d_in[18];
    const float* b_out_w   = (const float*)d_in[19];
    float* out = (float*)d_out;

    // ---- workspace layout with liveness overlap (~207 MiB) ----
    char* ws = (char*)d_ws;
    u16*  xnb    = (u16*)ws;   ws += (size_t)T * DMODEL * 2;
    u16*  zb     = (u16*)ws;   ws += (size_t)2 * T * DINNER * 2;
    u16*  xbcraw = (u16*)ws;   ws += (size_t)2 * T * CONVCH * 2;   // dead after conv -> y
    u16*  xbcb   = (u16*)ws;   ws += (size_t)2 * T * CONVCH * 2;   // dead after chunk -> Mcomb
    u16*  xdtb   = (u16*)ws;   ws += (size_t)2 * T * DINNER * 2;   // dead after chunk -> ybb
    float* dtb   = (float*)ws; ws += (size_t)2 * T * NH * 4;
    float* acs   = (float*)ws; ws += (size_t)2 * BATCH * NH * NCH * CHUNK * 4;
    float* cd    = (float*)ws; ws += (size_t)2 * BATCH * NH * NCH * 4;
    u16*  stb    = (u16*)ws;   ws += (size_t)2 * N_ST * 2;
    u16*  inwb   = (u16*)ws;   ws += (size_t)2 * N_INW * 2;
    u16*  fowT2  = (u16*)ws;   ws += (size_t)2 * N_OUTW * 2;
    u16*  owbb   = (u16*)ws;   ws += (size_t)N_OUTW * 2;
    // aliases
    u16*  yb16  = xbcraw;
    u16*  ybb   = xdtb;
    u16*  Mcomb = xbcb;

    k_prep<<<1024 + F2B_BLOCKS + TW_BLOCKS, 256, 0, stream>>>(
        x, norm_w, f_in_w, b_in_w, f_dt_bias, b_dt_bias, xnb, dtb,
        out_w_blk, f_out_w, b_out_w, inwb, owbb, fowT2);

    // in-proj main: 8-phase 256x256, 512 blocks, XCD-swizzled panel assignment
    {
        dim3 g(T / 256, 16, 2);
        k_mm_in8<<<g, 512, 0, stream>>>(xnb, inwb, zb, xbcraw);
    }
    // in-proj cleanup: 17th n-panel (cols 4096..4351), proven 128x128 structure
    {
        dim3 g(T / 128, 2, 2);
        k_mm_in<<<g, 256, 0, stream>>>(xnb, inwb, zb, xbcraw, 32);
    }
    {
        dim3 g(((T / 4) * (CONVCH / 8) + 255) / 256, 1, 2);
        k_conv<<<g, 256, 0, stream>>>(xbcraw, f_conv_w, b_conv_w, f_conv_b, b_conv_b,
                                      dtb, xbcb, xdtb);
    }
    {
        dim3 g(BATCH * NCH * NH, 1, 2);
        k_states<<<g, 256, 0, stream>>>(xbcb, xdtb, dtb, f_A_log, b_A_log, acs, cd, stb);
    }
    k_scan<<<(2 * BATCH * NH * HD * DSTATE) / 256, 256, 0, stream>>>(stb, cd);
    {
        dim3 g(BATCH * NCH * NH, 1, 2);
        k_chunk<<<g, 256, 0, stream>>>(xbcb, xdtb, acs, stb, f_D, b_D, yb16);
    }
    {
        dim3 g(T / 4, 1, 2);
        k_gate<<<g, 256, 0, stream>>>(yb16, zb, f_gnorm_w, b_gnorm_w, ybb);
    }
    k_mm64<<<512, 256, 0, stream>>>(owbb, fowT2, Mcomb);
    k_mm_fin8<<<256, 512, 0, stream>>>(ybb, ybb + (size_t)T * DINNER, Mcomb,
                                       out, out_b_blk, x);
}

// Round 10
// 474.630 us; speedup vs baseline: 1.0407x; 1.0407x over previous
//
#include <hip/hip_runtime.h>
#include <hip/hip_bf16.h>
#include <math.h>

#define BATCH 2
#define SEQL 2048
#define T 4096            // BATCH*SEQL tokens
#define DMODEL 1024
#define DINNER 2048
#define DSTATE 128
#define NH 32
#define HD 64
#define DPROJ2 4352       // z (2048) + xBC (2304); dt handled separately in fp32
#define CONVCH 2304
#define NCH 16            // chunks per sequence
#define CHUNK 128
#define EPS 1e-5f

#define N_INW ((size_t)DPROJ2 * DMODEL)   // 4,456,448
#define N_OUTW ((size_t)DMODEL * DINNER)  // 2,097,152
#define N_ST ((size_t)BATCH * NCH * NH * HD * DSTATE)  // 8,388,608 per dir
#define F2B_BLOCKS 10752   // (2*N_INW + N_OUTW)/4/256
#define TW_BLOCKS 1024     // 32 x 16 x 2

typedef unsigned short u16;
typedef __bf16 bf16x8 __attribute__((ext_vector_type(8)));
typedef float f32x4 __attribute__((ext_vector_type(4)));

__device__ __forceinline__ u16 f2b(float f) {
    union { float f; unsigned u; } v; v.f = f;
    unsigned r = v.u + 0x7fffu + ((v.u >> 16) & 1u);
    return (u16)(r >> 16);
}
__device__ __forceinline__ float b2f(u16 b) {
    union { unsigned u; float f; } v; v.u = ((unsigned)b) << 16;
    return v.f;
}
__device__ __forceinline__ float lo16f(unsigned u) {
    union { unsigned x; float f; } v; v.x = u << 16; return v.f;
}
__device__ __forceinline__ float hi16f(unsigned u) {
    union { unsigned x; float f; } v; v.x = u & 0xffff0000u; return v.f;
}
__device__ __forceinline__ int flipseq(int r) {
    return (r & ~(SEQL - 1)) | ((SEQL - 1) - (r & (SEQL - 1)));
}
__device__ __forceinline__ void gload16(const u16* g, u16* l) {
    __builtin_amdgcn_global_load_lds(
        (const __attribute__((address_space(1))) void*)g,
        (__attribute__((address_space(3))) void*)l, 16, 0, 0);
}

#define FENCE asm volatile("" ::: "memory")

// ---------------- merged prep: [0,1024) rmsnorm+dt rows; [1024,..) weight f2b/transpose ----------------
__global__ __launch_bounds__(256) void k_prep(
    const float* __restrict__ x, const float* __restrict__ w,
    const float* __restrict__ f_in_w, const float* __restrict__ b_in_w,
    const float* __restrict__ dtb_f, const float* __restrict__ dtb_b,
    u16* __restrict__ outb, float* __restrict__ dt,
    const float* __restrict__ out_w_blk,
    const float* __restrict__ f_out_w, const float* __restrict__ b_out_w,
    u16* __restrict__ d_inwb, u16* __restrict__ d_owbb, u16* __restrict__ d_fowT)
{
    __shared__ float xs[4][1024];
    __shared__ u16 t[64][65];
    int bid0 = blockIdx.x;
    int tid = threadIdx.x;
    if (bid0 < 1024) {
        // ---- rmsnorm + dt path ----
        int r0 = bid0 * 4;
        int lane = tid & 63, wv = tid >> 6;
        int row = r0 + wv;
        const float* xr = x + (size_t)row * DMODEL;
        float4 v[4];
        float ss = 0.f;
        #pragma unroll
        for (int i = 0; i < 4; ++i) {
            v[i] = *(const float4*)(xr + (i * 64 + lane) * 4);
            ss += v[i].x * v[i].x + v[i].y * v[i].y + v[i].z * v[i].z + v[i].w * v[i].w;
        }
        #pragma unroll
        for (int off = 32; off > 0; off >>= 1) ss += __shfl_down(ss, off);
        ss = __shfl(ss, 0);
        float sc = rsqrtf(ss / DMODEL + EPS);
        #pragma unroll
        for (int i = 0; i < 4; ++i) {
            int c = (i * 64 + lane) * 4;
            float4 wv4 = *(const float4*)(w + c);
            ushort4 o;
            o.x = f2b(v[i].x * sc * wv4.x);
            o.y = f2b(v[i].y * sc * wv4.y);
            o.z = f2b(v[i].z * sc * wv4.z);
            o.w = f2b(v[i].w * sc * wv4.w);
            *(ushort4*)(outb + (size_t)row * DMODEL + c) = o;
            xs[wv][c + 0] = b2f(o.x); xs[wv][c + 1] = b2f(o.y);
            xs[wv][c + 2] = b2f(o.z); xs[wv][c + 3] = b2f(o.w);
        }
        __syncthreads();
        // dt phase: thread group of 4 per (dir,h); float4 weight loads (64 iters)
        int h2 = tid >> 2, part = tid & 3;
        int dir = h2 >> 5, h = h2 & 31;
        const float* wd = (dir ? b_in_w : f_in_w) + (size_t)(DPROJ2 + h) * DMODEL;
        float a0 = 0.f, a1 = 0.f, a2 = 0.f, a3 = 0.f;
        #pragma unroll 4
        for (int kk = 0; kk < 64; ++kk) {
            int k = part * 4 + (kk << 4);
            float4 wv4 = *(const float4*)(wd + k);
            a0 += xs[0][k] * wv4.x + xs[0][k + 1] * wv4.y + xs[0][k + 2] * wv4.z + xs[0][k + 3] * wv4.w;
            a1 += xs[1][k] * wv4.x + xs[1][k + 1] * wv4.y + xs[1][k + 2] * wv4.z + xs[1][k + 3] * wv4.w;
            a2 += xs[2][k] * wv4.x + xs[2][k + 1] * wv4.y + xs[2][k + 2] * wv4.z + xs[2][k + 3] * wv4.w;
            a3 += xs[3][k] * wv4.x + xs[3][k + 1] * wv4.y + xs[3][k + 2] * wv4.z + xs[3][k + 3] * wv4.w;
        }
        #pragma unroll
        for (int off = 2; off > 0; off >>= 1) {
            a0 += __shfl_down(a0, off, 4); a1 += __shfl_down(a1, off, 4);
            a2 += __shfl_down(a2, off, 4); a3 += __shfl_down(a3, off, 4);
        }
        if (part == 0) {
            float bsh = dir ? dtb_b[h] : dtb_f[h];
            float* dtp = dt + (size_t)dir * T * NH;
            float vv[4] = {a0, a1, a2, a3};
            #pragma unroll
            for (int rr = 0; rr < 4; ++rr) {
                int rg = r0 + rr;
                if (dir) rg = flipseq(rg);
                float vvv = vv[rr] + bsh;
                dtp[(size_t)rg * NH + h] = (vvv > 20.f) ? vvv : log1pf(expf(vvv));
            }
        }
        return;
    }
    // ---- weight prep path ----
    int bid = bid0 - 1024;
    if (bid < F2B_BLOCKS) {
        size_t i = ((size_t)bid * 256 + tid) * 4;
        const float* s; u16* d; size_t off;
        if (i < 2 * N_INW) {
            int dir = i >= N_INW;
            off = i - (size_t)dir * N_INW;
            s = dir ? b_in_w : f_in_w; d = d_inwb + (size_t)dir * N_INW;
        } else {
            off = i - 2 * N_INW;
            if (off >= N_OUTW) return;
            s = out_w_blk; d = d_owbb;
        }
        float4 v = *(const float4*)(s + off);
        ushort4 o;
        o.x = f2b(v.x); o.y = f2b(v.y); o.z = f2b(v.z); o.w = f2b(v.w);
        *(ushort4*)(d + off) = o;
        return;
    }
    int b2 = bid - F2B_BLOCKS;
    int dir = b2 >> 9;
    int rem = b2 & 511;
    int c0 = (rem & 31) * 64, e0 = (rem >> 5) * 64;
    const float* src = dir ? b_out_w : f_out_w;
    u16* d = d_fowT + (size_t)dir * N_OUTW;
    for (int i = tid; i < 64 * 16; i += 256) {
        int el = i >> 4, c4 = (i & 15) * 4;
        float4 v = *(const float4*)(src + (size_t)(e0 + el) * DINNER + c0 + c4);
        t[c4 + 0][el] = f2b(v.x); t[c4 + 1][el] = f2b(v.y);
        t[c4 + 2][el] = f2b(v.z); t[c4 + 3][el] = f2b(v.w);
    }
    __syncthreads();
    for (int i = tid; i < 64 * 16; i += 256) {
        int cl = i >> 4, e4 = (i & 15) * 4;
        ushort4 o;
        o.x = t[cl][e4]; o.y = t[cl][e4 + 1]; o.z = t[cl][e4 + 2]; o.w = t[cl][e4 + 3];
        *(ushort4*)(d + (size_t)(c0 + cl) * DMODEL + e0 + e4) = o;
    }
}

// ---------------- in-proj main: 256x256 tile, BK=64, 8-wave 8-phase pipelined MFMA GEMM ----------------
__global__ __launch_bounds__(512, 2) void k_mm_in8(
    const u16* __restrict__ A, const u16* __restrict__ W0,
    u16* __restrict__ zb0, u16* __restrict__ xbcraw0)
{
    __shared__ u16 lds_[8 * 8192];   // 128 KiB: [dbuf(2)][A/B(2)][half(2)] x 128x64 bf16
    int dir = blockIdx.z;
    const u16* W = W0 + (size_t)dir * N_INW;

    int f = blockIdx.x + (blockIdx.y << 4);   // 0..255 within dir; xcd = f & 7
    int xcd = f & 7;
    int jj = f >> 3;                          // 0..31
    int m0 = (jj >> 1) * 256;
    int n0 = ((xcd << 1) | (jj & 1)) * 256;

    u16* Cout; int ldcc, nbase;
    if (n0 < DINNER) {
        Cout = zb0 + (size_t)dir * T * DINNER;
        ldcc = DINNER;
        nbase = n0;
    } else {
        Cout = xbcraw0 + (size_t)dir * T * CONVCH;
        ldcc = CONVCH;
        nbase = n0 - DINNER;
    }

    int tid = threadIdx.x;
    int lane = tid & 63;
    int w = tid >> 6;          // 0..7
    int wm = w >> 2;           // 0..1  (M half: 128 rows)
    int wn = w & 3;            // 0..3  (N slice: 64 cols)
    int l15 = lane & 15;
    int gsw0 = (((lane >> 4) ^ (lane & 7)) << 3);        // ks = 0
    int gsw1 = (((4 + (lane >> 4)) ^ (lane & 7)) << 3);  // ks = 1

    const u16* pA[2][2];
    const u16* pB[2][2];
    int swz = ((lane & 7) ^ (lane >> 3)) << 3;   // pre-swizzled global column granule
    #pragma unroll
    for (int h = 0; h < 2; ++h)
        #pragma unroll
        for (int c = 0; c < 2; ++c) {
            int rl = (w * 2 + c) * 8 + (lane >> 3);     // 0..127 within half
            int grow = m0 + h * 128 + rl;
            if (dir) grow = flipseq(grow);
            pA[h][c] = A + (size_t)grow * DMODEL + swz;
            pB[h][c] = W + (size_t)(n0 + h * 128 + rl) * DMODEL + swz;
        }
    int dst0 = (w * 2 + 0) * 512 + lane * 8;
    int dst1 = (w * 2 + 1) * 512 + lane * 8;

#define STAGE_A(t_, h_) do { \
        gload16(pA[h_][0] + (t_) * 64, lds_ + (((t_) & 1) * 4 + (h_)) * 8192 + dst0); \
        gload16(pA[h_][1] + (t_) * 64, lds_ + (((t_) & 1) * 4 + (h_)) * 8192 + dst1); \
    } while (0)
#define STAGE_B(t_, h_) do { \
        gload16(pB[h_][0] + (t_) * 64, lds_ + (((t_) & 1) * 4 + 2 + (h_)) * 8192 + dst0); \
        gload16(pB[h_][1] + (t_) * 64, lds_ + (((t_) & 1) * 4 + 2 + (h_)) * 8192 + dst1); \
    } while (0)

    f32x4 acc[8][4] = {};
    bf16x8 bfv[4][2];

    STAGE_A(0, 0); STAGE_A(0, 1); STAGE_B(0, 0); STAGE_B(0, 1);
    FENCE;
    STAGE_B(1, 0); STAGE_B(1, 1);
    asm volatile("s_waitcnt vmcnt(4)" ::: "memory");
    __builtin_amdgcn_s_barrier();
    FENCE;

    for (int kt = 0; kt < 16; ++kt) {
        int d = kt & 1;
        const u16* Ab = lds_ + (d * 4 + wm) * 8192;
        const u16* Bb = lds_ + (d * 4 + 2 + (wn >> 1)) * 8192;
        int nrow0 = (wn & 1) * 64;
        #pragma unroll
        for (int q = 0; q < 4; ++q) {
            if (q == 0) {
                #pragma unroll
                for (int j = 0; j < 4; ++j) {
                    const u16* bp = Bb + (nrow0 + j * 16 + l15) * 64;
                    bfv[j][0] = *(const bf16x8*)(bp + gsw0);
                    bfv[j][1] = *(const bf16x8*)(bp + gsw1);
                }
            }
            const u16* ap0 = Ab + ((q * 2 + 0) * 16 + l15) * 64;
            const u16* ap1 = Ab + ((q * 2 + 1) * 16 + l15) * 64;
            bf16x8 a0k0 = *(const bf16x8*)(ap0 + gsw0);
            bf16x8 a0k1 = *(const bf16x8*)(ap0 + gsw1);
            bf16x8 a1k0 = *(const bf16x8*)(ap1 + gsw0);
            bf16x8 a1k1 = *(const bf16x8*)(ap1 + gsw1);
            if (q == 0)      { if (kt < 15) STAGE_A(kt + 1, 0); }
            else if (q == 1) { if (kt < 15) STAGE_A(kt + 1, 1); }
            else if (q == 2) { if (kt < 14) STAGE_B(kt + 2, 0); }
            else             { if (kt < 14) STAGE_B(kt + 2, 1); }
            FENCE;
            __builtin_amdgcn_s_barrier();
            asm volatile("s_waitcnt lgkmcnt(0)" ::: "memory");
            __builtin_amdgcn_s_setprio(1);
            #pragma unroll
            for (int j = 0; j < 4; ++j) {
                acc[q * 2 + 0][j] = __builtin_amdgcn_mfma_f32_16x16x32_bf16(a0k0, bfv[j][0], acc[q * 2 + 0][j], 0, 0, 0);
                acc[q * 2 + 0][j] = __builtin_amdgcn_mfma_f32_16x16x32_bf16(a0k1, bfv[j][1], acc[q * 2 + 0][j], 0, 0, 0);
                acc[q * 2 + 1][j] = __builtin_amdgcn_mfma_f32_16x16x32_bf16(a1k0, bfv[j][0], acc[q * 2 + 1][j], 0, 0, 0);
                acc[q * 2 + 1][j] = __builtin_amdgcn_mfma_f32_16x16x32_bf16(a1k1, bfv[j][1], acc[q * 2 + 1][j], 0, 0, 0);
            }
            __builtin_amdgcn_s_setprio(0);
            if (q == 3) {
                if (kt < 14)       asm volatile("s_waitcnt vmcnt(4)" ::: "memory");
                else if (kt == 14) asm volatile("s_waitcnt vmcnt(0)" ::: "memory");
            }
            FENCE;
            __builtin_amdgcn_s_barrier();
            FENCE;
        }
    }
#undef STAGE_A
#undef STAGE_B

    int rb = m0 + wm * 128 + ((lane >> 4) << 2);
    int cb = nbase + wn * 64 + l15;
    #pragma unroll
    for (int i = 0; i < 8; ++i)
        #pragma unroll
        for (int j = 0; j < 4; ++j)
            #pragma unroll
            for (int r = 0; r < 4; ++r)
                Cout[(size_t)(rb + i * 16 + r) * ldcc + cb + j * 16] = f2b(acc[i][j][r]);
}

// ---------------- in-proj cleanup: bf16 MFMA GEMM 128x128, BK=64, z = dir (proven m97-structure) ----------------
__global__ __launch_bounds__(256, 4) void k_mm_in(
    const u16* __restrict__ A, const u16* __restrict__ W0,
    u16* __restrict__ zb0, u16* __restrict__ xbcraw0, int ny0)
{
    const int K = DMODEL;
    int dir = blockIdx.z;
    const u16* W = W0 + (size_t)dir * N_INW;
    int m0 = blockIdx.x * 128, n0 = (blockIdx.y + ny0) * 128;

    u16* Cout;
    int ldcc, nbase;
    if (n0 < DINNER) {
        Cout = zb0 + (size_t)dir * T * DINNER;
        ldcc = DINNER;
        nbase = n0;
    } else {
        Cout = xbcraw0 + (size_t)dir * T * CONVCH;
        ldcc = CONVCH;
        nbase = n0 - DINNER;
    }

    __shared__ u16 As[2 * 128 * 32];
    __shared__ u16 Bs[2 * 128 * 32];
    int tid = threadIdx.x;
    int lane = tid & 63;
    int wrow = ((tid >> 6) & 1) * 64, wcol = (tid >> 7) * 64;

    int srow = tid >> 2, skof = (tid & 3) * 8;
    int ar1 = m0 + srow, ar2 = ar1 + 64;
    if (dir) { ar1 = flipseq(ar1); ar2 = flipseq(ar2); }
    const u16* ga1 = A + (size_t)ar1 * K + skof;
    const u16* ga2 = A + (size_t)ar2 * K + skof;
    const u16* gb1 = W + (size_t)(n0 + srow) * K + skof;
    const u16* gb2 = gb1 + (size_t)64 * K;
    u16* la1 = As + tid * 8;
    u16* la2 = As + 2048 + tid * 8;
    u16* lb1 = Bs + tid * 8;
    u16* lb2 = Bs + 2048 + tid * 8;

    int aoff[4], boff[4];
    #pragma unroll
    for (int i = 0; i < 4; ++i) {
        aoff[i] = (wrow + i * 16 + (lane & 15)) * 32 + ((lane >> 4) * 8);
        boff[i] = (wcol + i * 16 + (lane & 15)) * 32 + ((lane >> 4) * 8);
    }

    f32x4 acc[4][4] = {};
    for (int kt = 0; kt < K; kt += 64) {
        gload16(ga1, la1);        gload16(ga2, la2);
        gload16(ga1 + 32, la1 + 4096); gload16(ga2 + 32, la2 + 4096);
        gload16(gb1, lb1);        gload16(gb2, lb2);
        gload16(gb1 + 32, lb1 + 4096); gload16(gb2 + 32, lb2 + 4096);
        ga1 += 64; ga2 += 64; gb1 += 64; gb2 += 64;
        __syncthreads();
        #pragma unroll
        for (int ks = 0; ks < 2; ++ks) {
            bf16x8 af[4], bfv[4];
            #pragma unroll
            for (int i = 0; i < 4; ++i) af[i] = *(const bf16x8*)(As + ks * 4096 + aoff[i]);
            #pragma unroll
            for (int j = 0; j < 4; ++j) bfv[j] = *(const bf16x8*)(Bs + ks * 4096 + boff[j]);
            #pragma unroll
            for (int i = 0; i < 4; ++i)
                #pragma unroll
                for (int j = 0; j < 4; ++j)
                    acc[i][j] = __builtin_amdgcn_mfma_f32_16x16x32_bf16(af[i], bfv[j], acc[i][j], 0, 0, 0);
        }
        __syncthreads();
    }

    int rbase = m0 + wrow + ((lane >> 4) << 2);
    int cbase = nbase + wcol + (lane & 15);
    #pragma unroll
    for (int i = 0; i < 4; ++i)
        #pragma unroll
        for (int j = 0; j < 4; ++j)
            #pragma unroll
            for (int r = 0; r < 4; ++r)
                Cout[(size_t)(rbase + i * 16 + r) * ldcc + cbase + j * 16] = f2b(acc[i][j][r]);
}

// ---------------- weight-fold GEMM: Mcomb_dir = owbb[:, dir*1024:] @ fowT_dir^T ----------------
__global__ __launch_bounds__(256) void k_mm64(
    const u16* __restrict__ A0, const u16* __restrict__ W0,
    u16* __restrict__ Cb)
{
    int bid = blockIdx.x;
    int xcd = bid & 7;
    int j9 = bid >> 3;               // 0..63
    int dir = j9 >> 5;
    int m0 = xcd * 128;
    int n0 = (j9 & 31) * 64;
    const u16* A = A0 + dir * DMODEL;                 // column offset in 2048-wide rows
    const u16* W = W0 + (size_t)dir * N_OUTW;

    __shared__ u16 As[2 * 128 * 32];   // 8192 u16
    __shared__ u16 Bs[2 * 64 * 32];    // 4096 u16
    int tid = threadIdx.x;
    int lane = tid & 63;
    int w = tid >> 6;
    int wrow = (w & 1) * 64, wcol = (w >> 1) * 32;

    int srow = tid >> 2, skof = (tid & 3) * 8;
    const u16* ga1 = A + (size_t)(m0 + srow) * 2048 + skof;
    const u16* ga2 = A + (size_t)(m0 + 64 + srow) * 2048 + skof;
    const u16* gb  = W + (size_t)(n0 + srow) * DMODEL + skof;
    u16* la1 = As + tid * 8;
    u16* la2 = As + 2048 + tid * 8;
    u16* lb  = Bs + tid * 8;

    int aoff[4], boff[2];
    #pragma unroll
    for (int i = 0; i < 4; ++i)
        aoff[i] = (wrow + i * 16 + (lane & 15)) * 32 + ((lane >> 4) * 8);
    #pragma unroll
    for (int j = 0; j < 2; ++j)
        boff[j] = (wcol + j * 16 + (lane & 15)) * 32 + ((lane >> 4) * 8);

    f32x4 acc[4][2] = {};
    for (int kt = 0; kt < DMODEL; kt += 64) {
        gload16(ga1, la1); gload16(ga1 + 32, la1 + 4096);
        gload16(ga2, la2); gload16(ga2 + 32, la2 + 4096);
        gload16(gb, lb);   gload16(gb + 32, lb + 2048);
        ga1 += 64; ga2 += 64; gb += 64;
        __syncthreads();
        #pragma unroll
        for (int ks = 0; ks < 2; ++ks) {
            bf16x8 af[4], bfv[2];
            #pragma unroll
            for (int i = 0; i < 4; ++i) af[i] = *(const bf16x8*)(As + ks * 4096 + aoff[i]);
            #pragma unroll
            for (int j = 0; j < 2; ++j) bfv[j] = *(const bf16x8*)(Bs + ks * 2048 + boff[j]);
            #pragma unroll
            for (int i = 0; i < 4; ++i)
                #pragma unroll
                for (int j = 0; j < 2; ++j)
                    acc[i][j] = __builtin_amdgcn_mfma_f32_16x16x32_bf16(af[i], bfv[j], acc[i][j], 0, 0, 0);
        }
        __syncthreads();
    }

    int rbase = m0 + wrow + ((lane >> 4) << 2);
    int cbase = n0 + wcol + (lane & 15);
    #pragma unroll
    for (int i = 0; i < 4; ++i)
        #pragma unroll
        for (int j = 0; j < 2; ++j)
            #pragma unroll
            for (int r = 0; r < 4; ++r)
                Cb[(size_t)(rbase + i * 16 + r) * 4096 + dir * 2048 + cbase + j * 16] = f2b(acc[i][j][r]);
}

// ---------------- final fused GEMM: 8-phase pipelined clone of k_mm_in8 ----------------
__global__ __launch_bounds__(512, 2) void k_mm_fin8(
    const u16* __restrict__ A1, const u16* __restrict__ A2,
    const u16* __restrict__ W,      // Mcomb: 1024 x 4096 (Mf | Mb), k-contig
    float* __restrict__ out, const float* __restrict__ bias,
    const float* __restrict__ resid)
{
    __shared__ u16 lds_[8 * 8192];   // 128 KiB: [dbuf(2)][{A1,A2,B1,B2}] x 128x64 bf16
    int bid = blockIdx.x;
    int xcd = bid & 7;
    int j9 = bid >> 3;                  // 0..31
    int m0 = (xcd * 4 + (j9 & 3)) * 128;
    int n0 = (j9 >> 2) * 128;
    int tid = threadIdx.x;
    int lane = tid & 63;
    int w = tid >> 6;          // 0..7
    int wm = w >> 2;           // 0..1  (64-row half)
    int wn = w & 3;            // 0..3  (32-col slice)
    int l15 = lane & 15;
    int gsw0 = (((lane >> 4) ^ (lane & 7)) << 3);
    int gsw1 = (((4 + (lane >> 4)) ^ (lane & 7)) << 3);

    const u16* p[4][2];
    int swz = ((lane & 7) ^ (lane >> 3)) << 3;
    #pragma unroll
    for (int c = 0; c < 2; ++c) {
        int rl = (w * 2 + c) * 8 + (lane >> 3);     // 0..127
        p[0][c] = A1 + (size_t)(m0 + rl) * DINNER + swz;
        p[1][c] = A2 + (size_t)flipseq(m0 + rl) * DINNER + swz;
        p[2][c] = W + (size_t)(n0 + rl) * 4096 + swz;
        p[3][c] = p[2][c] + 2048;
    }
    int dst0 = (w * 2 + 0) * 512 + lane * 8;
    int dst1 = (w * 2 + 1) * 512 + lane * 8;

#define STG(t_, s_) do { \
        gload16(p[s_][0] + (t_) * 64, lds_ + (((t_) & 1) * 4 + (s_)) * 8192 + dst0); \
        gload16(p[s_][1] + (t_) * 64, lds_ + (((t_) & 1) * 4 + (s_)) * 8192 + dst1); \
    } while (0)

    f32x4 acc[4][2] = {};
    bf16x8 bf1[2][2], bf2[2][2];

    // prologue: tile0 all 4 half-tiles + tile1 B halves in flight
    STG(0, 0); STG(0, 1); STG(0, 2); STG(0, 3);
    FENCE;
    STG(1, 2); STG(1, 3);
    asm volatile("s_waitcnt vmcnt(4)" ::: "memory");
    __builtin_amdgcn_s_barrier();
    FENCE;

    for (int kt = 0; kt < 32; ++kt) {
        int d = kt & 1;
        const u16* A1b = lds_ + (d * 4 + 0) * 8192;
        const u16* A2b = lds_ + (d * 4 + 1) * 8192;
        const u16* B1b = lds_ + (d * 4 + 2) * 8192;
        const u16* B2b = lds_ + (d * 4 + 3) * 8192;
        #pragma unroll
        for (int ph = 0; ph < 2; ++ph) {
            if (ph == 0) {
                #pragma unroll
                for (int j = 0; j < 2; ++j) {
                    const u16* bp1 = B1b + (wn * 32 + j * 16 + l15) * 64;
                    const u16* bp2 = B2b + (wn * 32 + j * 16 + l15) * 64;
                    bf1[j][0] = *(const bf16x8*)(bp1 + gsw0);
                    bf1[j][1] = *(const bf16x8*)(bp1 + gsw1);
                    bf2[j][0] = *(const bf16x8*)(bp2 + gsw0);
                    bf2[j][1] = *(const bf16x8*)(bp2 + gsw1);
                }
            }
            bf16x8 a1[2][2], a2[2][2];
            #pragma unroll
            for (int i = 0; i < 2; ++i) {
                int ro = (wm * 64 + (ph * 2 + i) * 16 + l15) * 64;
                a1[i][0] = *(const bf16x8*)(A1b + ro + gsw0);
                a1[i][1] = *(const bf16x8*)(A1b + ro + gsw1);
                a2[i][0] = *(const bf16x8*)(A2b + ro + gsw0);
                a2[i][1] = *(const bf16x8*)(A2b + ro + gsw1);
            }
            if (ph == 0) { if (kt < 31) { STG(kt + 1, 0); STG(kt + 1, 1); } }
            else         { if (kt < 30) { STG(kt + 2, 2); STG(kt + 2, 3); } }
            FENCE;
            __builtin_amdgcn_s_barrier();
            asm volatile("s_waitcnt lgkmcnt(0)" ::: "memory");
            __builtin_amdgcn_s_setprio(1);
            #pragma unroll
            for (int i = 0; i < 2; ++i)
                #pragma unroll
                for (int j = 0; j < 2; ++j) {
                    int q = ph * 2 + i;
                    acc[q][j] = __builtin_amdgcn_mfma_f32_16x16x32_bf16(a1[i][0], bf1[j][0], acc[q][j], 0, 0, 0);
                    acc[q][j] = __builtin_amdgcn_mfma_f32_16x16x32_bf16(a1[i][1], bf1[j][1], acc[q][j], 0, 0, 0);
                    acc[q][j] = __builtin_amdgcn_mfma_f32_16x16x32_bf16(a2[i][0], bf2[j][0], acc[q][j], 0, 0, 0);
                    acc[q][j] = __builtin_amdgcn_mfma_f32_16x16x32_bf16(a2[i][1], bf2[j][1], acc[q][j], 0, 0, 0);
                }
            __builtin_amdgcn_s_setprio(0);
            if (ph == 1) {
                if (kt < 30)       asm volatile("s_waitcnt vmcnt(4)" ::: "memory");
                else if (kt == 30) asm volatile("s_waitcnt vmcnt(0)" ::: "memory");
            }
            FENCE;
            __builtin_amdgcn_s_barrier();
            FENCE;
        }
    }
#undef STG

    int rb = m0 + wm * 64 + ((lane >> 4) << 2);
    int cb = n0 + wn * 32 + l15;
    #pragma unroll
    for (int i = 0; i < 4; ++i)
        #pragma unroll
        for (int j = 0; j < 2; ++j)
            #pragma unroll
            for (int r = 0; r < 4; ++r) {
                int row = rb + i * 16 + r, col = cb + j * 16;
                out[(size_t)row * DMODEL + col] =
                    acc[i][j][r] + bias[col] + resid[(size_t)row * DMODEL + col];
            }
}

// ---------------- conv4 + silu, 4 rows x 8 ch per thread (sliding window); z = dir ----------------
__global__ void k_conv(const u16* __restrict__ xraw0,
                       const float* __restrict__ cw_f, const float* __restrict__ cw_b,
                       const float* __restrict__ cb_f, const float* __restrict__ cb_b,
                       const float* __restrict__ dt0,
                       u16* __restrict__ xbcb0, u16* __restrict__ xdtb0)
{
    int dir = blockIdx.z;
    const u16* xraw = xraw0 + (size_t)dir * T * CONVCH;
    const float* cw = dir ? cw_b : cw_f;
    const float* cb = dir ? cb_b : cb_f;
    const float* dt = dt0 + (size_t)dir * T * NH;
    u16* xbcb = xbcb0 + (size_t)dir * T * CONVCH;
    u16* xdtb = xdtb0 + (size_t)dir * T * DINNER;

    int idx = blockIdx.x * blockDim.x + threadIdx.x;
    if (idx >= (T / 4) * (CONVCH / 8)) return;
    int r4 = idx / (CONVCH / 8);
    int c8 = (idx - r4 * (CONVCH / 8)) * 8;
    int r0 = r4 * 4;                  // 4 rows, all within one sequence (SEQL % 4 == 0)
    int t0 = r0 & (SEQL - 1);

    float4 cwv[8];
    #pragma unroll
    for (int j = 0; j < 8; ++j) cwv[j] = *(const float4*)(cw + (size_t)(c8 + j) * 4);
    float acc[4][8];
    {
        float4 c0 = *(const float4*)(cb + c8);
        float4 c1 = *(const float4*)(cb + c8 + 4);
        #pragma unroll
        for (int i = 0; i < 4; ++i) {
            acc[i][0] = c0.x; acc[i][1] = c0.y; acc[i][2] = c0.z; acc[i][3] = c0.w;
            acc[i][4] = c1.x; acc[i][5] = c1.y; acc[i][6] = c1.z; acc[i][7] = c1.w;
        }
    }
    // source rows s = 0..6 map to global row r0 - 3 + s; output i uses tap j = s - i
    #pragma unroll
    for (int s = 0; s < 7; ++s) {
        int tt = t0 - 3 + s;
        if (tt < 0) continue;        // pre-sequence padding (zero)
        const u16* src = xraw + (size_t)(r0 - 3 + s) * CONVCH + c8;
        ushort4 v0 = *(const ushort4*)src;
        ushort4 v1 = *(const ushort4*)(src + 4);
        float xv[8] = {b2f(v0.x), b2f(v0.y), b2f(v0.z), b2f(v0.w),
                       b2f(v1.x), b2f(v1.y), b2f(v1.z), b2f(v1.w)};
        #pragma unroll
        for (int i = 0; i < 4; ++i) {
            if (i <= s && i >= s - 3) {     // compile-time after unroll
                const int j = s - i;        // tap index 0..3
                #pragma unroll
                for (int ch = 0; ch < 8; ++ch) {
                    float wv = (j == 0) ? cwv[ch].x : (j == 1) ? cwv[ch].y
                             : (j == 2) ? cwv[ch].z : cwv[ch].w;
                    acc[i][ch] += xv[ch] * wv;
                }
            }
        }
    }
    #pragma unroll
    for (int i = 0; i < 4; ++i) {
        int r = r0 + i;
        float sgl[8];
        #pragma unroll
        for (int ch = 0; ch < 8; ++ch) sgl[ch] = acc[i][ch] / (1.f + __expf(-acc[i][ch]));
        ushort4 o0, o1;
        o0.x = f2b(sgl[0]); o0.y = f2b(sgl[1]); o0.z = f2b(sgl[2]); o0.w = f2b(sgl[3]);
        o1.x = f2b(sgl[4]); o1.y = f2b(sgl[5]); o1.z = f2b(sgl[6]); o1.w = f2b(sgl[7]);
        *(ushort4*)(xbcb + (size_t)r * CONVCH + c8) = o0;
        *(ushort4*)(xbcb + (size_t)r * CONVCH + c8 + 4) = o1;
        if (c8 < DINNER) {
            float dv = dt[(size_t)r * NH + (c8 >> 6)];
            ushort4 d0, d1;
            d0.x = f2b(sgl[0] * dv); d0.y = f2b(sgl[1] * dv);
            d0.z = f2b(sgl[2] * dv); d0.w = f2b(sgl[3] * dv);
            d1.x = f2b(sgl[4] * dv); d1.y = f2b(sgl[5] * dv);
            d1.z = f2b(sgl[6] * dv); d1.w = f2b(sgl[7] * dv);
            *(ushort4*)(xdtb + (size_t)r * DINNER + c8) = d0;
            *(ushort4*)(xdtb + (size_t)r * DINNER + c8 + 4) = d1;
        }
    }
}

#define LDW 136
// ---------------- states + inline acs: cumsum, st = (X*dt)^T @ (B*dec); z = dir ----------------
// Scan via per-wave __shfl_up inclusive scan (2 barriers) instead of 14-barrier Hillis-Steele.
__global__ __launch_bounds__(256) void k_states(
    const u16* __restrict__ xbcb0, const u16* __restrict__ xdtb0,
    const float* __restrict__ dt0,
    const float* __restrict__ Alog_f, const float* __restrict__ Alog_b,
    float* __restrict__ acs0, float* __restrict__ cd0, u16* __restrict__ st0)
{
    int dir = blockIdx.z;
    const u16* xbcb = xbcb0 + (size_t)dir * T * CONVCH;
    const u16* xdtb = xdtb0 + (size_t)dir * T * DINNER;
    const float* dt = dt0 + (size_t)dir * T * NH;
    const float* A_log = dir ? Alog_b : Alog_f;
    float* acs = acs0 + (size_t)dir * BATCH * NH * NCH * CHUNK;
    float* cd = cd0 + (size_t)dir * BATCH * NH * NCH;
    u16* st = st0 + (size_t)dir * N_ST;

    __shared__ u16 Bt[128 * LDW];
    __shared__ u16 Xt[64 * LDW];
    __shared__ float cs[128];
    __shared__ float dec_s[128];
    int tid = threadIdx.x;
    int lane = tid & 63;
    int w = tid >> 6;
    int h = blockIdx.x & 31;
    int bc = blockIdx.x >> 5;
    int c = bc & 15, b = bc >> 4;
    int row0 = b * SEQL + c * CHUNK;

    float val = 0.f;
    if (tid < 128) {
        float Ah = -expf(A_log[h]);
        val = Ah * dt[(size_t)(row0 + tid) * NH + h];
    }
    for (int i = tid; i < 128 * 16; i += 256) {
        int l = i >> 4, pg = (i & 15) * 4;
        ushort4 v = *(const ushort4*)(xdtb + (size_t)(row0 + l) * DINNER + h * HD + pg);
        Xt[(pg + 0) * LDW + l] = v.x; Xt[(pg + 1) * LDW + l] = v.y;
        Xt[(pg + 2) * LDW + l] = v.z; Xt[(pg + 3) * LDW + l] = v.w;
    }
    // per-wave inclusive scan (waves 0,1 carry rows 0-63 / 64-127)
    #pragma unroll
    for (int off = 1; off < 64; off <<= 1) {
        float n = __shfl_up(val, off);
        if (lane >= off) val += n;
    }
    if (tid < 128) cs[tid] = val;
    __syncthreads();                       // also covers Xt staging
    if (tid >= 64 && tid < 128) {
        val += cs[63];
        cs[tid] = val;
    }
    __syncthreads();
    size_t abase = ((size_t)(b * NH + h) * NCH + c) << 7;
    if (tid < 128) acs[abase + tid] = cs[tid];
    float a_last = cs[127];
    if (tid == 127) cd[(b * NH + h) * NCH + c] = expf(a_last);
    if (tid < 128) dec_s[tid] = __expf(a_last - cs[tid]);
    __syncthreads();
    for (int i = tid; i < 128 * 32; i += 256) {
        int l = i >> 5, ng = (i & 31) * 4;
        ushort4 v = *(const ushort4*)(xbcb + (size_t)(row0 + l) * CONVCH + DINNER + ng);
        float d = dec_s[l];
        Bt[(ng + 0) * LDW + l] = f2b(b2f(v.x) * d);
        Bt[(ng + 1) * LDW + l] = f2b(b2f(v.y) * d);
        Bt[(ng + 2) * LDW + l] = f2b(b2f(v.z) * d);
        Bt[(ng + 3) * LDW + l] = f2b(b2f(v.w) * d);
    }
    __syncthreads();
    f32x4 tacc[8] = {};
    for (int kk = 0; kk < 4; ++kk) {
        bf16x8 afs = *(const bf16x8*)(Xt + (w * 16 + (lane & 15)) * LDW
                                      + kk * 32 + (lane >> 4) * 8);
        #pragma unroll
        for (int j = 0; j < 8; ++j) {
            bf16x8 bfs = *(const bf16x8*)(Bt + (j * 16 + (lane & 15)) * LDW
                                          + kk * 32 + (lane >> 4) * 8);
            tacc[j] = __builtin_amdgcn_mfma_f32_16x16x32_bf16(afs, bfs, tacc[j], 0, 0, 0);
        }
    }
    size_t sb = (size_t)blockIdx.x * (HD * DSTATE);
    #pragma unroll
    for (int j = 0; j < 8; ++j)
        #pragma unroll
        for (int r = 0; r < 4; ++r) {
            int p = w * 16 + (lane >> 4) * 4 + r;
            int n = j * 16 + (lane & 15);
            st[sb + (size_t)p * DSTATE + n] = f2b(tacc[j][r]);
        }
}

// ---------------- inter-chunk scan (in place, bf16), both dirs ----------------
__global__ void k_scan(u16* __restrict__ st0, const float* __restrict__ cd0)
{
    int i = blockIdx.x * blockDim.x + threadIdx.x;
    if (i >= 2 * BATCH * NH * HD * DSTATE) return;
    int dir = i >> 19;
    int j = i & ((1 << 19) - 1);
    u16* st = st0 + (size_t)dir * N_ST;
    const float* cd = cd0 + (size_t)dir * BATCH * NH * NCH;
    int n = j & 127;
    int rest = j >> 7;
    int p = rest & 63; rest >>= 6;
    int h = rest & 31;
    int b = rest >> 5;
    float s = 0.f;
    for (int c = 0; c < NCH; ++c) {
        size_t idx = ((size_t)((b * NCH + c) * NH + h) * HD + p) * DSTATE + n;
        float v = b2f(st[idx]);
        st[idx] = f2b(s);
        s = s * cd[(b * NH + h) * NCH + c] + v;
    }
}

// ---------------- fused per-(b,c,h): Y_diag + Y_off + xh*D -> y (single write); z = dir ----------------
// (round-8 form: coalesced prev->LDS staging between barriers. Direct-global prev read
// regressed +17us: prev is per-block-unique -> no L2 reuse, strided fragment loads expose
// HBM latency on the MFMA critical path at 21% occupancy.)
__global__ __launch_bounds__(256) void k_chunk(
    const u16* __restrict__ xbcb0, const u16* __restrict__ xdtb0,
    const float* __restrict__ acs0, const u16* __restrict__ prev0,
    const float* __restrict__ D_f, const float* __restrict__ D_b,
    u16* __restrict__ y0)
{
    int dir = blockIdx.z;
    const u16* xbcb = xbcb0 + (size_t)dir * T * CONVCH;
    const u16* xdtb = xdtb0 + (size_t)dir * T * DINNER;
    const float* acs = acs0 + (size_t)dir * BATCH * NH * NCH * CHUNK;
    const u16* prev = prev0 + (size_t)dir * N_ST;
    const float* Dp = dir ? D_b : D_f;
    u16* y = y0 + (size_t)dir * T * DINNER;

    __shared__ u16 S0[128 * LDW];
    __shared__ u16 Xt[64 * LDW];
    __shared__ float acs_s[128];
    int tid = threadIdx.x;
    int lane = tid & 63;
    int w = tid >> 6;
    int h = blockIdx.x & 31;
    int bc = blockIdx.x >> 5;
    int c = bc & 15, b = bc >> 4;
    int row0 = b * SEQL + c * CHUNK;

    if (tid < 128)
        acs_s[tid] = acs[(((size_t)(b * NH + h) * NCH + c) << 7) + tid];
    for (int i = tid; i < 128 * 16; i += 256) {
        int s = i >> 4, m8 = (i & 15) * 8;
        *(uint4*)(S0 + s * LDW + m8) =
            *(const uint4*)(xbcb + (size_t)(row0 + s) * CONVCH + DINNER + m8);
    }
    for (int i = tid; i < 128 * 16; i += 256) {
        int l = i >> 4, pg = (i & 15) * 4;
        ushort4 v = *(const ushort4*)(xdtb + (size_t)(row0 + l) * DINNER + h * HD + pg);
        Xt[(pg + 0) * LDW + l] = v.x; Xt[(pg + 1) * LDW + l] = v.y;
        Xt[(pg + 2) * LDW + l] = v.z; Xt[(pg + 3) * LDW + l] = v.w;
    }
    __syncthreads();

    int wrow = (w & 1) * 64, wcol = (w >> 1) * 64;
    const u16* cbase = xbcb + (size_t)row0 * CONVCH + DINNER + DSTATE;
    f32x4 sacc[4][4] = {};
    for (int kk = 0; kk < 4; ++kk) {
        bf16x8 af[4], bfr[4];
        #pragma unroll
        for (int i = 0; i < 4; ++i)
            af[i] = *(const bf16x8*)(cbase + (size_t)(wrow + i * 16 + (lane & 15)) * CONVCH
                                     + kk * 32 + (lane >> 4) * 8);
        #pragma unroll
        for (int j = 0; j < 4; ++j)
            bfr[j] = *(const bf16x8*)(S0 + (wcol + j * 16 + (lane & 15)) * LDW
                                      + kk * 32 + (lane >> 4) * 8);
        #pragma unroll
        for (int i = 0; i < 4; ++i)
            #pragma unroll
            for (int j = 0; j < 4; ++j)
                if (wcol + j * 16 <= wrow + i * 16 + 15)
                    sacc[i][j] = __builtin_amdgcn_mfma_f32_16x16x32_bf16(af[i], bfr[j], sacc[i][j], 0, 0, 0);
    }
    __syncthreads();
    #pragma unroll
    for (int i = 0; i < 4; ++i)
        #pragma unroll
        for (int j = 0; j < 4; ++j) {
            int s = wcol + j * 16 + (lane & 15);
            #pragma unroll
            for (int r = 0; r < 4; ++r) {
                int l = wrow + i * 16 + (lane >> 4) * 4 + r;
                float v = (s <= l) ? sacc[i][j][r] * __expf(acs_s[l] - acs_s[s]) : 0.f;
                S0[l * LDW + s] = f2b(v);
            }
        }
    __syncthreads();
    f32x4 yacc[2][4] = {};
    for (int kk = 0; kk < 4; ++kk) {
        bf16x8 af[2], bfr[4];
        #pragma unroll
        for (int i = 0; i < 2; ++i)
            af[i] = *(const bf16x8*)(S0 + (w * 32 + i * 16 + (lane & 15)) * LDW
                                     + kk * 32 + (lane >> 4) * 8);
        #pragma unroll
        for (int j = 0; j < 4; ++j)
            bfr[j] = *(const bf16x8*)(Xt + (j * 16 + (lane & 15)) * LDW
                                      + kk * 32 + (lane >> 4) * 8);
        #pragma unroll
        for (int i = 0; i < 2; ++i)
            #pragma unroll
            for (int j = 0; j < 4; ++j)
                yacc[i][j] = __builtin_amdgcn_mfma_f32_16x16x32_bf16(af[i], bfr[j], yacc[i][j], 0, 0, 0);
    }
    __syncthreads();
    size_t sb = (size_t)blockIdx.x * (HD * DSTATE);
    for (int i = tid; i < 64 * 16; i += 256) {
        int p = i >> 4, m8 = (i & 15) * 8;
        *(uint4*)(S0 + p * LDW + m8) = *(const uint4*)(prev + sb + (size_t)p * DSTATE + m8);
    }
    __syncthreads();
    f32x4 oacc[2][4] = {};
    for (int kk = 0; kk < 4; ++kk) {
        bf16x8 af[2], bfr[4];
        #pragma unroll
        for (int i = 0; i < 2; ++i)
            af[i] = *(const bf16x8*)(cbase + (size_t)(w * 32 + i * 16 + (lane & 15)) * CONVCH
                                     + kk * 32 + (lane >> 4) * 8);
        #pragma unroll
        for (int j = 0; j < 4; ++j)
            bfr[j] = *(const bf16x8*)(S0 + (j * 16 + (lane & 15)) * LDW
                                      + kk * 32 + (lane >> 4) * 8);
        #pragma unroll
        for (int i = 0; i < 2; ++i)
            #pragma unroll
            for (int j = 0; j < 4; ++j)
                oacc[i][j] = __builtin_amdgcn_mfma_f32_16x16x32_bf16(af[i], bfr[j], oacc[i][j], 0, 0, 0);
    }
    float Dh = Dp[h];
    #pragma unroll
    for (int i = 0; i < 2; ++i)
        #pragma unroll
        for (int j = 0; j < 4; ++j)
            #pragma unroll
            for (int r = 0; r < 4; ++r) {
                int l = w * 32 + i * 16 + (lane >> 4) * 4 + r;
                int p = j * 16 + (lane & 15);
                float val = yacc[i][j][r] + __expf(acs_s[l]) * oacc[i][j][r]
                          + b2f(xbcb[(size_t)(row0 + l) * CONVCH + h * HD + p]) * Dh;
                y[(size_t)(row0 + l) * DINNER + h * HD + p] = f2b(val);
            }
}

// ---------------- gated rmsnorm: wave-per-row, barrier-free; z = dir ----------------
__global__ __launch_bounds__(256) void k_gate(
    const u16* __restrict__ y0, const u16* __restrict__ zb0,
    const float* __restrict__ gw_f, const float* __restrict__ gw_b,
    u16* __restrict__ out0)
{
    int dir = blockIdx.z;
    const float* gw = dir ? gw_b : gw_f;
    int lane = threadIdx.x & 63;
    int r = blockIdx.x * 4 + (threadIdx.x >> 6);
    const u16* yr = y0 + (size_t)dir * T * DINNER + (size_t)r * DINNER;
    const u16* zr = zb0 + (size_t)dir * T * DINNER + (size_t)r * DINNER;
    u16* outr = out0 + (size_t)dir * T * DINNER + (size_t)r * DINNER;

    float tv[32];
    float ss = 0.f;
    #pragma unroll
    for (int it = 0; it < 4; ++it) {
        int i = (it * 64 + lane) * 8;
        uint4 yv = *(const uint4*)(yr + i);
        uint4 zv = *(const uint4*)(zr + i);
        unsigned yu[4] = {yv.x, yv.y, yv.z, yv.w};
        unsigned zu[4] = {zv.x, zv.y, zv.z, zv.w};
        #pragma unroll
        for (int k = 0; k < 4; ++k) {
            float ya = lo16f(yu[k]), yb = hi16f(yu[k]);
            float za = lo16f(zu[k]), zc = hi16f(zu[k]);
            float ta = ya * (za / (1.f + __expf(-za)));
            float tb = yb * (zc / (1.f + __expf(-zc)));
            tv[it * 8 + k * 2 + 0] = ta;
            tv[it * 8 + k * 2 + 1] = tb;
            ss += ta * ta + tb * tb;
        }
    }
    #pragma unroll
    for (int off = 32; off > 0; off >>= 1) ss += __shfl_xor(ss, off);
    float sc = rsqrtf(ss / DINNER + EPS);
    #pragma unroll
    for (int it = 0; it < 4; ++it) {
        int i = (it * 64 + lane) * 8;
        float4 g0 = *(const float4*)(gw + i);
        float4 g1 = *(const float4*)(gw + i + 4);
        float gg[8] = {g0.x, g0.y, g0.z, g0.w, g1.x, g1.y, g1.z, g1.w};
        uint4 o;
        unsigned ov[4];
        #pragma unroll
        for (int k = 0; k < 4; ++k) {
            unsigned a = f2b(tv[it * 8 + k * 2 + 0] * sc * gg[k * 2 + 0]);
            unsigned bq = f2b(tv[it * 8 + k * 2 + 1] * sc * gg[k * 2 + 1]);
            ov[k] = a | (bq << 16);
        }
        o.x = ov[0]; o.y = ov[1]; o.z = ov[2]; o.w = ov[3];
        *(uint4*)(outr + i) = o;
    }
}

// ---------------- launch ----------------
extern "C" void kernel_launch(void* const* d_in, const int* in_sizes, int n_in,
                              void* d_out, int out_size, void* d_ws, size_t ws_size,
                              hipStream_t stream)
{
    const float* x         = (const float*)d_in[0];
    const float* norm_w    = (const float*)d_in[1];
    const float* out_w_blk = (const float*)d_in[2];
    const float* out_b_blk = (const float*)d_in[3];
    const float* f_in_w    = (const float*)d_in[4];
    const float* f_conv_w  = (const float*)d_in[5];
    const float* f_conv_b  = (const float*)d_in[6];
    const float* f_dt_bias = (const float*)d_in[7];
    const float* f_A_log   = (const float*)d_in[8];
    const float* f_D       = (const float*)d_in[9];
    const float* f_gnorm_w = (const float*)d_in[10];
    const float* f_out_w   = (const float*)d_in[11];
    const float* b_in_w    = (const float*)d_in[12];
    const float* b_conv_w  = (const float*)d_in[13];
    const float* b_conv_b  = (const float*)d_in[14];
    const float* b_dt_bias = (const float*)d_in[15];
    const float* b_A_log   = (const float*)d_in[16];
    const float* b_D       = (const float*)d_in[17];
    const float* b_gnorm_w = (const float*)d_in[18];
    const float* b_out_w   = (const float*)d_in[19];
    float* out = (float*)d_out;

    // ---- workspace layout with liveness overlap (~207 MiB) ----
    char* ws = (char*)d_ws;
    u16*  xnb    = (u16*)ws;   ws += (size_t)T * DMODEL * 2;
    u16*  zb     = (u16*)ws;   ws += (size_t)2 * T * DINNER * 2;
    u16*  xbcraw = (u16*)ws;   ws += (size_t)2 * T * CONVCH * 2;   // dead after conv -> y
    u16*  xbcb   = (u16*)ws;   ws += (size_t)2 * T * CONVCH * 2;   // dead after chunk -> Mcomb
    u16*  xdtb   = (u16*)ws;   ws += (size_t)2 * T * DINNER * 2;   // dead after chunk -> ybb
    float* dtb   = (float*)ws; ws += (size_t)2 * T * NH * 4;
    float* acs   = (float*)ws; ws += (size_t)2 * BATCH * NH * NCH * CHUNK * 4;
    float* cd    = (float*)ws; ws += (size_t)2 * BATCH * NH * NCH * 4;
    u16*  stb    = (u16*)ws;   ws += (size_t)2 * N_ST * 2;
    u16*  inwb   = (u16*)ws;   ws += (size_t)2 * N_INW * 2;
    u16*  fowT2  = (u16*)ws;   ws += (size_t)2 * N_OUTW * 2;
    u16*  owbb   = (u16*)ws;   ws += (size_t)N_OUTW * 2;
    // aliases
    u16*  yb16  = xbcraw;
    u16*  ybb   = xdtb;
    u16*  Mcomb = xbcb;

    k_prep<<<1024 + F2B_BLOCKS + TW_BLOCKS, 256, 0, stream>>>(
        x, norm_w, f_in_w, b_in_w, f_dt_bias, b_dt_bias, xnb, dtb,
        out_w_blk, f_out_w, b_out_w, inwb, owbb, fowT2);

    // in-proj main: 8-phase 256x256, 512 blocks, XCD-swizzled panel assignment
    {
        dim3 g(T / 256, 16, 2);
        k_mm_in8<<<g, 512, 0, stream>>>(xnb, inwb, zb, xbcraw);
    }
    // in-proj cleanup: 17th n-panel (cols 4096..4351), proven 128x128 structure
    {
        dim3 g(T / 128, 2, 2);
        k_mm_in<<<g, 256, 0, stream>>>(xnb, inwb, zb, xbcraw, 32);
    }
    {
        dim3 g(((T / 4) * (CONVCH / 8) + 255) / 256, 1, 2);
        k_conv<<<g, 256, 0, stream>>>(xbcraw, f_conv_w, b_conv_w, f_conv_b, b_conv_b,
                                      dtb, xbcb, xdtb);
    }
    {
        dim3 g(BATCH * NCH * NH, 1, 2);
        k_states<<<g, 256, 0, stream>>>(xbcb, xdtb, dtb, f_A_log, b_A_log, acs, cd, stb);
    }
    k_scan<<<(2 * BATCH * NH * HD * DSTATE) / 256, 256, 0, stream>>>(stb, cd);
    {
        dim3 g(BATCH * NCH * NH, 1, 2);
        k_chunk<<<g, 256, 0, stream>>>(xbcb, xdtb, acs, stb, f_D, b_D, yb16);
    }
    {
        dim3 g(T / 4, 1, 2);
        k_gate<<<g, 256, 0, stream>>>(yb16, zb, f_gnorm_w, b_gnorm_w, ybb);
    }
    k_mm64<<<512, 256, 0, stream>>>(owbb, fowT2, Mcomb);
    k_mm_fin8<<<256, 512, 0, stream>>>(ybb, ybb + (size_t)T * DINNER, Mcomb,
                                       out, out_b_blk, x);
}